// Round 3
// baseline (914.962 us; speedup 1.0000x reference)
//
#include <hip/hip_runtime.h>
#include <math.h>

#define S_LEN 4096
#define DMODEL 1024
#define NHEADS 16
#define DHEAD 64

typedef unsigned short u16;
typedef short bf16x8 __attribute__((ext_vector_type(8)));
typedef float f32x4 __attribute__((ext_vector_type(4)));
typedef u16 u16x8 __attribute__((ext_vector_type(8)));

__device__ __forceinline__ u16 f2bf(float f) {
    unsigned u = __builtin_bit_cast(unsigned, f);
    u = (u + 0x7FFFu + ((u >> 16) & 1u)) >> 16;
    return (u16)u;
}
__device__ __forceinline__ float bf2f(u16 b) {
    return __builtin_bit_cast(float, ((unsigned)b) << 16);
}

// ---------------- RoPE tables (fp32-faithful to numpy float32 path) ----------------
__global__ void rope_table_kernel(float* __restrict__ cost, float* __restrict__ sint) {
    int tid = blockIdx.x * blockDim.x + threadIdx.x;  // 4096*32
    int i = tid & 31;
    int pos = tid >> 5;
    double e = (double)(2 * i) / 64.0;
    float t32 = (float)pow(10000.0, e);   // correctly-rounded fp32 of 10000^e
    float freq = 1.0f / t32;              // fp32 division, matches ref
    float ang = (float)pos * freq;        // fp32 multiply, matches outer()
    cost[tid] = (float)cos((double)ang);  // CR fp32 cos of the exact fp32 angle
    sint[tid] = (float)sin((double)ang);
}

// split 8 fp32 -> hi/lo bf16
__device__ __forceinline__ void split8(const float* v, u16x8& h, u16x8& l) {
#pragma unroll
    for (int i = 0; i < 8; i++) {
        u16 hh = f2bf(v[i]);
        h[i] = hh;
        l[i] = f2bf(v[i] - bf2f(hh));
    }
}

// ---------------- split-GEMM QKV + fused RoPE ----------------
// C[128x128] tile of (A fp32 [4096][1024]) x (B fp32 [1024][1024])^T with
// 3-term bf16 split (ah*bh + ah*bl + al*bh), fp32 accumulate.
// z=0 -> Q2 bf16 hi/lo [h][s][128] (RoPE applied), z=1 -> K2 same, z=2 -> V^T bf16 [h*64+dh][s].
__global__ __launch_bounds__(256) void gemm_qkv_split_kernel(
        const float* __restrict__ x,
        const float* __restrict__ wq, const float* __restrict__ wk, const float* __restrict__ wv,
        const int* __restrict__ tp,
        const float* __restrict__ cost, const float* __restrict__ sint,
        u16* __restrict__ q2, u16* __restrict__ k2, u16* __restrict__ vtb) {
    __shared__ u16 sm[4][128 * 32];   // AH, AL, BH, BL
    const int z = blockIdx.z;
    const float* Bg = (z == 0) ? wq : (z == 1) ? wk : wv;
    const int m0 = blockIdx.y * 128, n0 = blockIdx.x * 128;

    const int tid = threadIdx.x;
    const int lane = tid & 63, wid = tid >> 6;
    const int wr = wid >> 1, wc = wid & 1;
    const int l15 = lane & 15, lhi = lane >> 4;

    f32x4 acc[4][4];
#pragma unroll
    for (int i = 0; i < 4; i++)
#pragma unroll
        for (int j = 0; j < 4; j++) acc[i][j] = (f32x4){0.f, 0.f, 0.f, 0.f};

    const int f = tid * 16;
    const int r = f >> 5, c = f & 31;

    for (int kt = 0; kt < 1024; kt += 32) {
        // stage A (x) split
        {
            size_t off = (size_t)(m0 + r) * 1024 + kt + c;
            float t[16];
            *(float4*)(t + 0)  = *(const float4*)(x + off);
            *(float4*)(t + 4)  = *(const float4*)(x + off + 4);
            *(float4*)(t + 8)  = *(const float4*)(x + off + 8);
            *(float4*)(t + 12) = *(const float4*)(x + off + 12);
            u16x8 h0, l0, h1, l1;
            split8(t, h0, l0);
            split8(t + 8, h1, l1);
            *(u16x8*)(sm[0] + f) = h0; *(u16x8*)(sm[0] + f + 8) = h1;
            *(u16x8*)(sm[1] + f) = l0; *(u16x8*)(sm[1] + f + 8) = l1;
        }
        // stage B (weight) split
        {
            size_t off = (size_t)(n0 + r) * 1024 + kt + c;
            float t[16];
            *(float4*)(t + 0)  = *(const float4*)(Bg + off);
            *(float4*)(t + 4)  = *(const float4*)(Bg + off + 4);
            *(float4*)(t + 8)  = *(const float4*)(Bg + off + 8);
            *(float4*)(t + 12) = *(const float4*)(Bg + off + 12);
            u16x8 h0, l0, h1, l1;
            split8(t, h0, l0);
            split8(t + 8, h1, l1);
            *(u16x8*)(sm[2] + f) = h0; *(u16x8*)(sm[2] + f + 8) = h1;
            *(u16x8*)(sm[3] + f) = l0; *(u16x8*)(sm[3] + f + 8) = l1;
        }
        __syncthreads();
        bf16x8 ah[4], al[4], bh[4], bl[4];
#pragma unroll
        for (int m = 0; m < 4; m++) {
            int row = wr * 64 + m * 16 + l15;
            ah[m] = *(const bf16x8*)(sm[0] + row * 32 + 8 * lhi);
            al[m] = *(const bf16x8*)(sm[1] + row * 32 + 8 * lhi);
        }
#pragma unroll
        for (int n = 0; n < 4; n++) {
            int row = wc * 64 + n * 16 + l15;
            bh[n] = *(const bf16x8*)(sm[2] + row * 32 + 8 * lhi);
            bl[n] = *(const bf16x8*)(sm[3] + row * 32 + 8 * lhi);
        }
#pragma unroll
        for (int m = 0; m < 4; m++)
#pragma unroll
            for (int n = 0; n < 4; n++) {
                acc[m][n] = __builtin_amdgcn_mfma_f32_16x16x32_bf16(al[m], bh[n], acc[m][n], 0, 0, 0);
                acc[m][n] = __builtin_amdgcn_mfma_f32_16x16x32_bf16(ah[m], bl[n], acc[m][n], 0, 0, 0);
                acc[m][n] = __builtin_amdgcn_mfma_f32_16x16x32_bf16(ah[m], bh[n], acc[m][n], 0, 0, 0);
            }
        __syncthreads();
    }

    if (z == 2) {
        // V^T bf16 [h*64+dh][s]
#pragma unroll
        for (int m = 0; m < 4; m++)
#pragma unroll
            for (int n = 0; n < 4; n++)
#pragma unroll
                for (int j = 0; j < 4; j++) {
                    int srow = m0 + wr * 64 + m * 16 + lhi * 4 + j;
                    int eg = n0 + wc * 64 + n * 16 + l15;
                    vtb[(size_t)eg * S_LEN + srow] = f2bf(acc[m][n][j]);
                }
        return;
    }

    // Q/K: fused RoPE (fp32) then hi/lo bf16 split -> [h][s][128]
    u16* outp = (z == 0) ? q2 : k2;
    const int head = (n0 + wc * 64) >> 6;
#pragma unroll
    for (int m = 0; m < 4; m++)
#pragma unroll
        for (int n = 0; n < 4; n++) {
            const int dh = n * 16 + l15;
            const int pairi = dh >> 1;
            const bool even = (dh & 1) == 0;
#pragma unroll
            for (int j = 0; j < 4; j++) {
                int srow = m0 + wr * 64 + m * 16 + lhi * 4 + j;
                float v = acc[m][n][j];
                float pv = __shfl_xor(v, 1);
                int pos = tp[srow];
                float cc = cost[(size_t)pos * 32 + pairi];
                float ss = sint[(size_t)pos * 32 + pairi];
                float e = even ? v : pv;
                float o = even ? pv : v;
                float res = even ? (e * cc - o * ss) : (e * ss + o * cc);
                u16 hb = f2bf(res);
                u16 lb = f2bf(res - bf2f(hb));
                size_t base = ((size_t)head * S_LEN + srow) * 128 + dh;
                outp[base] = hb;
                outp[base + 64] = lb;
            }
        }
}

// ---------------- Flash attention with bf16x3 QK^T ----------------
// Q2/K2: [h][s][128] bf16 rows = [hi 0..63][lo 64..127]. V: [h][64][s] bf16.
__global__ __launch_bounds__(256) void attn_kernel(const u16* __restrict__ q2,
                                                   const u16* __restrict__ k2,
                                                   const u16* __restrict__ vtb,
                                                   u16* __restrict__ attnb) {
    const int h = blockIdx.y;
    const int qblk = gridDim.x - 1 - blockIdx.x;
    const int wid = threadIdx.x >> 6;
    const int lane = threadIdx.x & 63;
    const int l15 = lane & 15, lhi = lane >> 4;
    const int q0 = qblk * 64 + wid * 16;

    const u16* Qh2 = q2 + (size_t)h * S_LEN * 128;
    const u16* Kh2 = k2 + (size_t)h * S_LEN * 128;
    const u16* Vh = vtb + (size_t)h * 64 * S_LEN;

    __shared__ u16 pl[4][16 * 64];
    u16* myP = pl[wid];

    bf16x8 qhf[2], qlf[2];
#pragma unroll
    for (int ks = 0; ks < 2; ks++) {
        const u16* qp = Qh2 + (size_t)(q0 + l15) * 128 + ks * 32 + 8 * lhi;
        qhf[ks] = *(const bf16x8*)(qp);
        qlf[ks] = *(const bf16x8*)(qp + 64);
    }

    f32x4 o_acc[4];
#pragma unroll
    for (int n = 0; n < 4; n++) o_acc[n] = (f32x4){0.f, 0.f, 0.f, 0.f};
    float m_run[4], l_run[4];
#pragma unroll
    for (int j = 0; j < 4; j++) { m_run[j] = -1e30f; l_run[j] = 0.f; }

    const int nkb = qblk + 1;
    for (int kblk = 0; kblk < nkb; kblk++) {
        const int k0 = kblk * 64;
        f32x4 sf[4];
#pragma unroll
        for (int n = 0; n < 4; n++) {
            const u16* kp = Kh2 + (size_t)(k0 + n * 16 + l15) * 128 + 8 * lhi;
            bf16x8 kh0 = *(const bf16x8*)(kp);
            bf16x8 kh1 = *(const bf16x8*)(kp + 32);
            bf16x8 kl0 = *(const bf16x8*)(kp + 64);
            bf16x8 kl1 = *(const bf16x8*)(kp + 96);
            f32x4 a = (f32x4){0.f, 0.f, 0.f, 0.f};
            a = __builtin_amdgcn_mfma_f32_16x16x32_bf16(qlf[0], kh0, a, 0, 0, 0);
            a = __builtin_amdgcn_mfma_f32_16x16x32_bf16(qlf[1], kh1, a, 0, 0, 0);
            a = __builtin_amdgcn_mfma_f32_16x16x32_bf16(qhf[0], kl0, a, 0, 0, 0);
            a = __builtin_amdgcn_mfma_f32_16x16x32_bf16(qhf[1], kl1, a, 0, 0, 0);
            a = __builtin_amdgcn_mfma_f32_16x16x32_bf16(qhf[0], kh0, a, 0, 0, 0);
            a = __builtin_amdgcn_mfma_f32_16x16x32_bf16(qhf[1], kh1, a, 0, 0, 0);
            sf[n] = a;
        }
        const bool last = (kblk == nkb - 1);
        float pmax[4];
#pragma unroll
        for (int j = 0; j < 4; j++) {
            int qg = q0 + lhi * 4 + j;
            float mx = -1e30f;
#pragma unroll
            for (int n = 0; n < 4; n++) {
                float v = sf[n][j] * 0.125f;
                if (last) {
                    int kg = k0 + n * 16 + l15;
                    if (kg > qg) v = -1e30f;
                }
                sf[n][j] = v;
                mx = fmaxf(mx, v);
            }
            mx = fmaxf(mx, __shfl_xor(mx, 1));
            mx = fmaxf(mx, __shfl_xor(mx, 2));
            mx = fmaxf(mx, __shfl_xor(mx, 4));
            mx = fmaxf(mx, __shfl_xor(mx, 8));
            pmax[j] = mx;
        }
#pragma unroll
        for (int j = 0; j < 4; j++) {
            float mn = fmaxf(m_run[j], pmax[j]);
            float alpha = __expf(m_run[j] - mn);
            float rs = 0.f;
#pragma unroll
            for (int n = 0; n < 4; n++) {
                float p = __expf(sf[n][j] - mn);
                sf[n][j] = p;
                rs += p;
            }
            rs += __shfl_xor(rs, 1);
            rs += __shfl_xor(rs, 2);
            rs += __shfl_xor(rs, 4);
            rs += __shfl_xor(rs, 8);
            l_run[j] = l_run[j] * alpha + rs;
            m_run[j] = mn;
#pragma unroll
            for (int n = 0; n < 4; n++) o_acc[n][j] *= alpha;
        }
#pragma unroll
        for (int n = 0; n < 4; n++)
#pragma unroll
            for (int j = 0; j < 4; j++)
                myP[(lhi * 4 + j) * 64 + n * 16 + l15] = f2bf(sf[n][j]);
        asm volatile("s_waitcnt lgkmcnt(0)" ::: "memory");
        __builtin_amdgcn_sched_barrier(0);
        bf16x8 pf[2];
        pf[0] = *(const bf16x8*)(myP + l15 * 64 + 8 * lhi);
        pf[1] = *(const bf16x8*)(myP + l15 * 64 + 32 + 8 * lhi);
#pragma unroll
        for (int n = 0; n < 4; n++) {
            const u16* vp = Vh + (size_t)(n * 16 + l15) * S_LEN + k0 + 8 * lhi;
            bf16x8 vf0 = *(const bf16x8*)(vp);
            bf16x8 vf1 = *(const bf16x8*)(vp + 32);
            o_acc[n] = __builtin_amdgcn_mfma_f32_16x16x32_bf16(pf[0], vf0, o_acc[n], 0, 0, 0);
            o_acc[n] = __builtin_amdgcn_mfma_f32_16x16x32_bf16(pf[1], vf1, o_acc[n], 0, 0, 0);
        }
    }
#pragma unroll
    for (int n = 0; n < 4; n++)
#pragma unroll
        for (int j = 0; j < 4; j++) {
            float v = o_acc[n][j] / l_run[j];
            int srow = q0 + lhi * 4 + j;
            attnb[(size_t)srow * 1024 + h * 64 + n * 16 + l15] = f2bf(v);
        }
}

// ---------------- output projection: attn bf16 x (w_o fp32 -> bf16)^T -> fp32 ----------------
__global__ __launch_bounds__(256) void gemm_out_kernel(const u16* __restrict__ attnb,
                                                       const float* __restrict__ wo,
                                                       float* __restrict__ out) {
    __shared__ u16 sA[128 * 32];
    __shared__ u16 sB[128 * 32];
    const int m0 = blockIdx.y * 128, n0 = blockIdx.x * 128;
    const int tid = threadIdx.x;
    const int lane = tid & 63, wid = tid >> 6;
    const int wr = wid >> 1, wc = wid & 1;
    const int l15 = lane & 15, lhi = lane >> 4;

    f32x4 acc[4][4];
#pragma unroll
    for (int i = 0; i < 4; i++)
#pragma unroll
        for (int j = 0; j < 4; j++) acc[i][j] = (f32x4){0.f, 0.f, 0.f, 0.f};

    const int f = tid * 16;
    const int r = f >> 5, c = f & 31;

    for (int kt = 0; kt < 1024; kt += 32) {
        *(bf16x8*)(sA + f)     = *(const bf16x8*)(attnb + (size_t)(m0 + r) * 1024 + kt + c);
        *(bf16x8*)(sA + f + 8) = *(const bf16x8*)(attnb + (size_t)(m0 + r) * 1024 + kt + c + 8);
        {
            size_t off = (size_t)(n0 + r) * 1024 + kt + c;
            float t[16];
            *(float4*)(t + 0)  = *(const float4*)(wo + off);
            *(float4*)(t + 4)  = *(const float4*)(wo + off + 4);
            *(float4*)(t + 8)  = *(const float4*)(wo + off + 8);
            *(float4*)(t + 12) = *(const float4*)(wo + off + 12);
            u16x8 h0, h1;
#pragma unroll
            for (int i = 0; i < 8; i++) h0[i] = f2bf(t[i]);
#pragma unroll
            for (int i = 0; i < 8; i++) h1[i] = f2bf(t[8 + i]);
            *(u16x8*)(sB + f) = h0;
            *(u16x8*)(sB + f + 8) = h1;
        }
        __syncthreads();
        bf16x8 af[4], bfr[4];
#pragma unroll
        for (int m = 0; m < 4; m++) {
            int row = wr * 64 + m * 16 + l15;
            af[m] = *(const bf16x8*)(sA + row * 32 + 8 * lhi);
        }
#pragma unroll
        for (int n = 0; n < 4; n++) {
            int row = wc * 64 + n * 16 + l15;
            bfr[n] = *(const bf16x8*)(sB + row * 32 + 8 * lhi);
        }
#pragma unroll
        for (int m = 0; m < 4; m++)
#pragma unroll
            for (int n = 0; n < 4; n++)
                acc[m][n] = __builtin_amdgcn_mfma_f32_16x16x32_bf16(af[m], bfr[n], acc[m][n], 0, 0, 0);
        __syncthreads();
    }

#pragma unroll
    for (int m = 0; m < 4; m++)
#pragma unroll
        for (int n = 0; n < 4; n++)
#pragma unroll
            for (int j = 0; j < 4; j++) {
                int srow = m0 + wr * 64 + m * 16 + lhi * 4 + j;
                int eg = n0 + wc * 64 + n * 16 + l15;
                out[(size_t)srow * 1024 + eg] = acc[m][n][j];
            }
}

// ---------------- host launch ----------------
extern "C" void kernel_launch(void* const* d_in, const int* in_sizes, int n_in,
                              void* d_out, int out_size, void* d_ws, size_t ws_size,
                              hipStream_t stream) {
    const float* x = (const float*)d_in[0];
    const int* tp = (const int*)d_in[1];
    const float* wq = (const float*)d_in[2];
    const float* wk = (const float*)d_in[3];
    const float* wv = (const float*)d_in[4];
    const float* wo = (const float*)d_in[5];
    float* out = (float*)d_out;
    char* ws = (char*)d_ws;

    // workspace layout (49 MiB total):
    u16* Q2    = (u16*)(ws + 0);           // 16 MiB bf16 [16][4096][128] hi/lo
    u16* K2    = (u16*)(ws + 16777216);    // 16 MiB
    u16* VTB   = (u16*)(ws + 33554432);    // 8 MiB bf16 [h*64+dh][4096]
    u16* ATTNB = (u16*)(ws + 41943040);    // 8 MiB bf16 [4096][1024]
    float* COST = (float*)(ws + 50331648); // 512 KiB
    float* SINT = (float*)(ws + 50855936); // 512 KiB

    rope_table_kernel<<<512, 256, 0, stream>>>(COST, SINT);

    gemm_qkv_split_kernel<<<dim3(8, 32, 3), 256, 0, stream>>>(
        x, wq, wk, wv, tp, COST, SINT, Q2, K2, VTB);

    attn_kernel<<<dim3(64, 16), 256, 0, stream>>>(Q2, K2, VTB, ATTNB);

    gemm_out_kernel<<<dim3(8, 32), 256, 0, stream>>>(ATTNB, wo, out);
}

// Round 4
// 645.597 us; speedup vs baseline: 1.4172x; 1.4172x over previous
//
#include <hip/hip_runtime.h>
#include <math.h>

#define S_LEN 4096
#define DMODEL 1024
#define NHEADS 16
#define DHEAD 64

typedef unsigned short u16;
typedef short bf16x8 __attribute__((ext_vector_type(8)));
typedef float f32x4 __attribute__((ext_vector_type(4)));
typedef u16 u16x8 __attribute__((ext_vector_type(8)));

__device__ __forceinline__ u16 f2bf(float f) {
    unsigned u = __builtin_bit_cast(unsigned, f);
    u = (u + 0x7FFFu + ((u >> 16) & 1u)) >> 16;
    return (u16)u;
}
__device__ __forceinline__ float bf2f(u16 b) {
    return __builtin_bit_cast(float, ((unsigned)b) << 16);
}

// ---------------- RoPE tables (fp32-faithful to numpy float32 path) ----------------
__global__ void rope_table_kernel(float* __restrict__ cost, float* __restrict__ sint) {
    int tid = blockIdx.x * blockDim.x + threadIdx.x;  // 4096*32
    int i = tid & 31;
    int pos = tid >> 5;
    double e = (double)(2 * i) / 64.0;
    float t32 = (float)pow(10000.0, e);
    float freq = 1.0f / t32;
    float ang = (float)pos * freq;
    cost[tid] = (float)cos((double)ang);
    sint[tid] = (float)sin((double)ang);
}

// split 8 fp32 -> hi/lo bf16
__device__ __forceinline__ void split8(const float* v, u16x8& h, u16x8& l) {
#pragma unroll
    for (int i = 0; i < 8; i++) {
        u16 hh = f2bf(v[i]);
        h[i] = hh;
        l[i] = f2bf(v[i] - bf2f(hh));
    }
}

// ---------------- split-GEMM QKV + fused RoPE ----------------
// z=0 -> Q2 bf16 hi/lo [h][s][128] (RoPE applied, pre-scaled by 1/8),
// z=1 -> K2 same (unscaled), z=2 -> V^T bf16 [h*64+dh][s].
__global__ __launch_bounds__(256) void gemm_qkv_split_kernel(
        const float* __restrict__ x,
        const float* __restrict__ wq, const float* __restrict__ wk, const float* __restrict__ wv,
        const int* __restrict__ tp,
        const float* __restrict__ cost, const float* __restrict__ sint,
        u16* __restrict__ q2, u16* __restrict__ k2, u16* __restrict__ vtb) {
    __shared__ u16 sm[4][128 * 32];   // AH, AL, BH, BL
    const int z = blockIdx.z;
    const float* Bg = (z == 0) ? wq : (z == 1) ? wk : wv;
    const int m0 = blockIdx.y * 128, n0 = blockIdx.x * 128;

    const int tid = threadIdx.x;
    const int lane = tid & 63, wid = tid >> 6;
    const int wr = wid >> 1, wc = wid & 1;
    const int l15 = lane & 15, lhi = lane >> 4;

    f32x4 acc[4][4];
#pragma unroll
    for (int i = 0; i < 4; i++)
#pragma unroll
        for (int j = 0; j < 4; j++) acc[i][j] = (f32x4){0.f, 0.f, 0.f, 0.f};

    const int f = tid * 16;
    const int r = f >> 5, c = f & 31;

    for (int kt = 0; kt < 1024; kt += 32) {
        {
            size_t off = (size_t)(m0 + r) * 1024 + kt + c;
            float t[16];
            *(float4*)(t + 0)  = *(const float4*)(x + off);
            *(float4*)(t + 4)  = *(const float4*)(x + off + 4);
            *(float4*)(t + 8)  = *(const float4*)(x + off + 8);
            *(float4*)(t + 12) = *(const float4*)(x + off + 12);
            u16x8 h0, l0, h1, l1;
            split8(t, h0, l0);
            split8(t + 8, h1, l1);
            *(u16x8*)(sm[0] + f) = h0; *(u16x8*)(sm[0] + f + 8) = h1;
            *(u16x8*)(sm[1] + f) = l0; *(u16x8*)(sm[1] + f + 8) = l1;
        }
        {
            size_t off = (size_t)(n0 + r) * 1024 + kt + c;
            float t[16];
            *(float4*)(t + 0)  = *(const float4*)(Bg + off);
            *(float4*)(t + 4)  = *(const float4*)(Bg + off + 4);
            *(float4*)(t + 8)  = *(const float4*)(Bg + off + 8);
            *(float4*)(t + 12) = *(const float4*)(Bg + off + 12);
            u16x8 h0, l0, h1, l1;
            split8(t, h0, l0);
            split8(t + 8, h1, l1);
            *(u16x8*)(sm[2] + f) = h0; *(u16x8*)(sm[2] + f + 8) = h1;
            *(u16x8*)(sm[3] + f) = l0; *(u16x8*)(sm[3] + f + 8) = l1;
        }
        __syncthreads();
        bf16x8 ah[4], al[4], bh[4], bl[4];
#pragma unroll
        for (int m = 0; m < 4; m++) {
            int row = wr * 64 + m * 16 + l15;
            ah[m] = *(const bf16x8*)(sm[0] + row * 32 + 8 * lhi);
            al[m] = *(const bf16x8*)(sm[1] + row * 32 + 8 * lhi);
        }
#pragma unroll
        for (int n = 0; n < 4; n++) {
            int row = wc * 64 + n * 16 + l15;
            bh[n] = *(const bf16x8*)(sm[2] + row * 32 + 8 * lhi);
            bl[n] = *(const bf16x8*)(sm[3] + row * 32 + 8 * lhi);
        }
#pragma unroll
        for (int m = 0; m < 4; m++)
#pragma unroll
            for (int n = 0; n < 4; n++) {
                acc[m][n] = __builtin_amdgcn_mfma_f32_16x16x32_bf16(al[m], bh[n], acc[m][n], 0, 0, 0);
                acc[m][n] = __builtin_amdgcn_mfma_f32_16x16x32_bf16(ah[m], bl[n], acc[m][n], 0, 0, 0);
                acc[m][n] = __builtin_amdgcn_mfma_f32_16x16x32_bf16(ah[m], bh[n], acc[m][n], 0, 0, 0);
            }
        __syncthreads();
    }

    if (z == 2) {
#pragma unroll
        for (int m = 0; m < 4; m++)
#pragma unroll
            for (int n = 0; n < 4; n++)
#pragma unroll
                for (int j = 0; j < 4; j++) {
                    int srow = m0 + wr * 64 + m * 16 + lhi * 4 + j;
                    int eg = n0 + wc * 64 + n * 16 + l15;
                    vtb[(size_t)eg * S_LEN + srow] = f2bf(acc[m][n][j]);
                }
        return;
    }

    u16* outp = (z == 0) ? q2 : k2;
    const float qscale = (z == 0) ? 0.125f : 1.0f;   // fold 1/sqrt(64) into Q (exact pow2)
    const int head = (n0 + wc * 64) >> 6;
#pragma unroll
    for (int m = 0; m < 4; m++)
#pragma unroll
        for (int n = 0; n < 4; n++) {
            const int dh = n * 16 + l15;
            const int pairi = dh >> 1;
            const bool even = (dh & 1) == 0;
#pragma unroll
            for (int j = 0; j < 4; j++) {
                int srow = m0 + wr * 64 + m * 16 + lhi * 4 + j;
                float v = acc[m][n][j];
                float pv = __shfl_xor(v, 1);
                int pos = tp[srow];
                float cc = cost[(size_t)pos * 32 + pairi];
                float ss = sint[(size_t)pos * 32 + pairi];
                float e = even ? v : pv;
                float o = even ? pv : v;
                float res = (even ? (e * cc - o * ss) : (e * ss + o * cc)) * qscale;
                u16 hb = f2bf(res);
                u16 lb = f2bf(res - bf2f(hb));
                size_t base = ((size_t)head * S_LEN + srow) * 128 + dh;
                outp[base] = hb;
                outp[base + 64] = lb;
            }
        }
}

// ---------------- Flash attention with bf16x3 QK^T ----------------
// Q2 (pre-scaled by 1/8) / K2: [h][s][128] bf16 = [hi 0..63][lo 64..127]. V: [h][64][s].
// grid (32,16); 4 waves; wave owns 32 q rows (2 groups of 16); KV block 64; no block sync.
__global__ __launch_bounds__(256) void attn_kernel(const u16* __restrict__ q2,
                                                   const u16* __restrict__ k2,
                                                   const u16* __restrict__ vtb,
                                                   u16* __restrict__ attnb) {
    const int h = blockIdx.y;
    const int qblk = gridDim.x - 1 - blockIdx.x;   // big tiles launch first
    const int wid = threadIdx.x >> 6;
    const int lane = threadIdx.x & 63;
    const int l15 = lane & 15, lhi = lane >> 4;
    const int q0 = qblk * 128 + wid * 32;          // wave's 32-row base

    const u16* Qh2 = q2 + (size_t)h * S_LEN * 128;
    const u16* Kh2 = k2 + (size_t)h * S_LEN * 128;
    const u16* Vh = vtb + (size_t)h * 64 * S_LEN;

    __shared__ u16 pl[4][32 * 64];
    u16* myP = pl[wid];

    // Q fragments per group g: row = q0+g*16+l15, d = ks*32 + 8*lhi (+0 hi, +64 lo)
    bf16x8 qhf[2][2], qlf[2][2];
#pragma unroll
    for (int g = 0; g < 2; g++)
#pragma unroll
        for (int ks = 0; ks < 2; ks++) {
            const u16* qp = Qh2 + (size_t)(q0 + g * 16 + l15) * 128 + ks * 32 + 8 * lhi;
            qhf[g][ks] = *(const bf16x8*)(qp);
            qlf[g][ks] = *(const bf16x8*)(qp + 64);
        }

    f32x4 o_acc[2][4];
#pragma unroll
    for (int g = 0; g < 2; g++)
#pragma unroll
        for (int n = 0; n < 4; n++) o_acc[g][n] = (f32x4){0.f, 0.f, 0.f, 0.f};
    float m_run[2][4], l_run[2][4];
#pragma unroll
    for (int g = 0; g < 2; g++)
#pragma unroll
        for (int j = 0; j < 4; j++) { m_run[g][j] = -1e30f; l_run[g][j] = 0.f; }

    const int nkb = ((q0 + 31) >> 6) + 1;          // per-wave kv blocks
    for (int kblk = 0; kblk < nkb; kblk++) {
        const int k0 = kblk * 64;
        f32x4 sf[2][4];
        // QK^T: K fragments shared by both groups
#pragma unroll
        for (int n = 0; n < 4; n++) {
            const u16* kp = Kh2 + (size_t)(k0 + n * 16 + l15) * 128 + 8 * lhi;
            bf16x8 kh0 = *(const bf16x8*)(kp);
            bf16x8 kh1 = *(const bf16x8*)(kp + 32);
            bf16x8 kl0 = *(const bf16x8*)(kp + 64);
            bf16x8 kl1 = *(const bf16x8*)(kp + 96);
#pragma unroll
            for (int g = 0; g < 2; g++) {
                f32x4 a = (f32x4){0.f, 0.f, 0.f, 0.f};
                a = __builtin_amdgcn_mfma_f32_16x16x32_bf16(qlf[g][0], kh0, a, 0, 0, 0);
                a = __builtin_amdgcn_mfma_f32_16x16x32_bf16(qlf[g][1], kh1, a, 0, 0, 0);
                a = __builtin_amdgcn_mfma_f32_16x16x32_bf16(qhf[g][0], kl0, a, 0, 0, 0);
                a = __builtin_amdgcn_mfma_f32_16x16x32_bf16(qhf[g][1], kl1, a, 0, 0, 0);
                a = __builtin_amdgcn_mfma_f32_16x16x32_bf16(qhf[g][0], kh0, a, 0, 0, 0);
                a = __builtin_amdgcn_mfma_f32_16x16x32_bf16(qhf[g][1], kh1, a, 0, 0, 0);
                sf[g][n] = a;
            }
        }
        const bool last = (kblk == nkb - 1);
        // online softmax per group (scores already scaled via Q)
#pragma unroll
        for (int g = 0; g < 2; g++) {
#pragma unroll
            for (int j = 0; j < 4; j++) {
                int qg = q0 + g * 16 + lhi * 4 + j;
                float mx = -1e30f;
#pragma unroll
                for (int n = 0; n < 4; n++) {
                    float v = sf[g][n][j];
                    if (last) {
                        int kg = k0 + n * 16 + l15;
                        if (kg > qg) v = -1e30f;
                    }
                    sf[g][n][j] = v;
                    mx = fmaxf(mx, v);
                }
                mx = fmaxf(mx, __shfl_xor(mx, 1));
                mx = fmaxf(mx, __shfl_xor(mx, 2));
                mx = fmaxf(mx, __shfl_xor(mx, 4));
                mx = fmaxf(mx, __shfl_xor(mx, 8));
                float mn = fmaxf(m_run[g][j], mx);
                float alpha = __expf(m_run[g][j] - mn);
                float rs = 0.f;
#pragma unroll
                for (int n = 0; n < 4; n++) {
                    float p = __expf(sf[g][n][j] - mn);
                    sf[g][n][j] = p;
                    rs += p;
                }
                rs += __shfl_xor(rs, 1);
                rs += __shfl_xor(rs, 2);
                rs += __shfl_xor(rs, 4);
                rs += __shfl_xor(rs, 8);
                l_run[g][j] = l_run[g][j] * alpha + rs;
                m_run[g][j] = mn;
#pragma unroll
                for (int n = 0; n < 4; n++) o_acc[g][n][j] *= alpha;
            }
            // P (C-layout) -> per-wave LDS (rows g*16 + lhi*4+j)
#pragma unroll
            for (int n = 0; n < 4; n++)
#pragma unroll
                for (int j = 0; j < 4; j++)
                    myP[(g * 16 + lhi * 4 + j) * 64 + n * 16 + l15] = f2bf(sf[g][n][j]);
        }
        // P A-fragments (compiler orders ds_read after aliasing ds_write; DS is in-order per wave)
        bf16x8 pf[2][2];
#pragma unroll
        for (int g = 0; g < 2; g++) {
            pf[g][0] = *(const bf16x8*)(myP + (g * 16 + l15) * 64 + 8 * lhi);
            pf[g][1] = *(const bf16x8*)(myP + (g * 16 + l15) * 64 + 32 + 8 * lhi);
        }
        // O += P V (V fragments shared by both groups)
#pragma unroll
        for (int n = 0; n < 4; n++) {
            const u16* vp = Vh + (size_t)(n * 16 + l15) * S_LEN + k0 + 8 * lhi;
            bf16x8 vf0 = *(const bf16x8*)(vp);
            bf16x8 vf1 = *(const bf16x8*)(vp + 32);
#pragma unroll
            for (int g = 0; g < 2; g++) {
                o_acc[g][n] = __builtin_amdgcn_mfma_f32_16x16x32_bf16(pf[g][0], vf0, o_acc[g][n], 0, 0, 0);
                o_acc[g][n] = __builtin_amdgcn_mfma_f32_16x16x32_bf16(pf[g][1], vf1, o_acc[g][n], 0, 0, 0);
            }
        }
    }
#pragma unroll
    for (int g = 0; g < 2; g++)
#pragma unroll
        for (int n = 0; n < 4; n++)
#pragma unroll
            for (int j = 0; j < 4; j++) {
                float v = o_acc[g][n][j] / l_run[g][j];
                int srow = q0 + g * 16 + lhi * 4 + j;
                attnb[(size_t)srow * 1024 + h * 64 + n * 16 + l15] = f2bf(v);
            }
}

// ---------------- output projection: attn bf16 x (w_o fp32 -> bf16)^T -> fp32 ----------------
__global__ __launch_bounds__(256) void gemm_out_kernel(const u16* __restrict__ attnb,
                                                       const float* __restrict__ wo,
                                                       float* __restrict__ out) {
    __shared__ u16 sA[128 * 32];
    __shared__ u16 sB[128 * 32];
    const int m0 = blockIdx.y * 128, n0 = blockIdx.x * 128;
    const int tid = threadIdx.x;
    const int lane = tid & 63, wid = tid >> 6;
    const int wr = wid >> 1, wc = wid & 1;
    const int l15 = lane & 15, lhi = lane >> 4;

    f32x4 acc[4][4];
#pragma unroll
    for (int i = 0; i < 4; i++)
#pragma unroll
        for (int j = 0; j < 4; j++) acc[i][j] = (f32x4){0.f, 0.f, 0.f, 0.f};

    const int f = tid * 16;
    const int r = f >> 5, c = f & 31;

    for (int kt = 0; kt < 1024; kt += 32) {
        *(bf16x8*)(sA + f)     = *(const bf16x8*)(attnb + (size_t)(m0 + r) * 1024 + kt + c);
        *(bf16x8*)(sA + f + 8) = *(const bf16x8*)(attnb + (size_t)(m0 + r) * 1024 + kt + c + 8);
        {
            size_t off = (size_t)(n0 + r) * 1024 + kt + c;
            float t[16];
            *(float4*)(t + 0)  = *(const float4*)(wo + off);
            *(float4*)(t + 4)  = *(const float4*)(wo + off + 4);
            *(float4*)(t + 8)  = *(const float4*)(wo + off + 8);
            *(float4*)(t + 12) = *(const float4*)(wo + off + 12);
            u16x8 h0, h1;
#pragma unroll
            for (int i = 0; i < 8; i++) h0[i] = f2bf(t[i]);
#pragma unroll
            for (int i = 0; i < 8; i++) h1[i] = f2bf(t[8 + i]);
            *(u16x8*)(sB + f) = h0;
            *(u16x8*)(sB + f + 8) = h1;
        }
        __syncthreads();
        bf16x8 af[4], bfr[4];
#pragma unroll
        for (int m = 0; m < 4; m++) {
            int row = wr * 64 + m * 16 + l15;
            af[m] = *(const bf16x8*)(sA + row * 32 + 8 * lhi);
        }
#pragma unroll
        for (int n = 0; n < 4; n++) {
            int row = wc * 64 + n * 16 + l15;
            bfr[n] = *(const bf16x8*)(sB + row * 32 + 8 * lhi);
        }
#pragma unroll
        for (int m = 0; m < 4; m++)
#pragma unroll
            for (int n = 0; n < 4; n++)
                acc[m][n] = __builtin_amdgcn_mfma_f32_16x16x32_bf16(af[m], bfr[n], acc[m][n], 0, 0, 0);
        __syncthreads();
    }

#pragma unroll
    for (int m = 0; m < 4; m++)
#pragma unroll
        for (int n = 0; n < 4; n++)
#pragma unroll
            for (int j = 0; j < 4; j++) {
                int srow = m0 + wr * 64 + m * 16 + lhi * 4 + j;
                int eg = n0 + wc * 64 + n * 16 + l15;
                out[(size_t)srow * 1024 + eg] = acc[m][n][j];
            }
}

// ---------------- host launch ----------------
extern "C" void kernel_launch(void* const* d_in, const int* in_sizes, int n_in,
                              void* d_out, int out_size, void* d_ws, size_t ws_size,
                              hipStream_t stream) {
    const float* x = (const float*)d_in[0];
    const int* tp = (const int*)d_in[1];
    const float* wq = (const float*)d_in[2];
    const float* wk = (const float*)d_in[3];
    const float* wv = (const float*)d_in[4];
    const float* wo = (const float*)d_in[5];
    float* out = (float*)d_out;
    char* ws = (char*)d_ws;

    u16* Q2    = (u16*)(ws + 0);           // 16 MiB bf16 [16][4096][128] hi/lo, pre-scaled 1/8
    u16* K2    = (u16*)(ws + 16777216);    // 16 MiB
    u16* VTB   = (u16*)(ws + 33554432);    // 8 MiB bf16 [h*64+dh][4096]
    u16* ATTNB = (u16*)(ws + 41943040);    // 8 MiB bf16 [4096][1024]
    float* COST = (float*)(ws + 50331648); // 512 KiB
    float* SINT = (float*)(ws + 50855936); // 512 KiB

    rope_table_kernel<<<512, 256, 0, stream>>>(COST, SINT);

    gemm_qkv_split_kernel<<<dim3(8, 32, 3), 256, 0, stream>>>(
        x, wq, wk, wv, tp, COST, SINT, Q2, K2, VTB);

    attn_kernel<<<dim3(32, 16), 256, 0, stream>>>(Q2, K2, VTB, ATTNB);

    gemm_out_kernel<<<dim3(8, 32), 256, 0, stream>>>(ATTNB, wo, out);
}

// Round 5
// 580.282 us; speedup vs baseline: 1.5768x; 1.1126x over previous
//
#include <hip/hip_runtime.h>
#include <math.h>

#define S_LEN 4096
#define DMODEL 1024
#define NHEADS 16
#define DHEAD 64

typedef unsigned short u16;
typedef short bf16x8 __attribute__((ext_vector_type(8)));
typedef float f32x4 __attribute__((ext_vector_type(4)));
typedef u16 u16x8 __attribute__((ext_vector_type(8)));
typedef unsigned uint4v __attribute__((ext_vector_type(4)));

__device__ __forceinline__ u16 f2bf(float f) {
    unsigned u = __builtin_bit_cast(unsigned, f);
    u = (u + 0x7FFFu + ((u >> 16) & 1u)) >> 16;
    return (u16)u;
}
__device__ __forceinline__ float bf2f(u16 b) {
    return __builtin_bit_cast(float, ((unsigned)b) << 16);
}

// ---------------- RoPE tables (fp32-faithful to numpy float32 path) ----------------
__global__ void rope_table_kernel(float* __restrict__ cost, float* __restrict__ sint) {
    int tid = blockIdx.x * blockDim.x + threadIdx.x;  // 4096*32
    int i = tid & 31;
    int pos = tid >> 5;
    double e = (double)(2 * i) / 64.0;
    float t32 = (float)pow(10000.0, e);
    float freq = 1.0f / t32;
    float ang = (float)pos * freq;
    cost[tid] = (float)cos((double)ang);
    sint[tid] = (float)sin((double)ang);
}

// split 8 fp32 -> hi/lo bf16
__device__ __forceinline__ void split8(const float* v, u16x8& h, u16x8& l) {
#pragma unroll
    for (int i = 0; i < 8; i++) {
        u16 hh = f2bf(v[i]);
        h[i] = hh;
        l[i] = f2bf(v[i] - bf2f(hh));
    }
}

// ---------------- split-GEMM QKV + fused RoPE ----------------
// z=0 -> Q2 bf16 hi/lo [h][s][128] (RoPE applied, pre-scaled by 1/8),
// z=1 -> K2 same (unscaled), z=2 -> V^T bf16 [h*64+dh][s].
__global__ __launch_bounds__(256) void gemm_qkv_split_kernel(
        const float* __restrict__ x,
        const float* __restrict__ wq, const float* __restrict__ wk, const float* __restrict__ wv,
        const int* __restrict__ tp,
        const float* __restrict__ cost, const float* __restrict__ sint,
        u16* __restrict__ q2, u16* __restrict__ k2, u16* __restrict__ vtb) {
    __shared__ u16 sm[4][128 * 32];   // AH, AL, BH, BL
    const int z = blockIdx.z;
    const float* Bg = (z == 0) ? wq : (z == 1) ? wk : wv;
    const int m0 = blockIdx.y * 128, n0 = blockIdx.x * 128;

    const int tid = threadIdx.x;
    const int lane = tid & 63, wid = tid >> 6;
    const int wr = wid >> 1, wc = wid & 1;
    const int l15 = lane & 15, lhi = lane >> 4;

    f32x4 acc[4][4];
#pragma unroll
    for (int i = 0; i < 4; i++)
#pragma unroll
        for (int j = 0; j < 4; j++) acc[i][j] = (f32x4){0.f, 0.f, 0.f, 0.f};

    const int f = tid * 16;
    const int r = f >> 5, c = f & 31;

    for (int kt = 0; kt < 1024; kt += 32) {
        {
            size_t off = (size_t)(m0 + r) * 1024 + kt + c;
            float t[16];
            *(float4*)(t + 0)  = *(const float4*)(x + off);
            *(float4*)(t + 4)  = *(const float4*)(x + off + 4);
            *(float4*)(t + 8)  = *(const float4*)(x + off + 8);
            *(float4*)(t + 12) = *(const float4*)(x + off + 12);
            u16x8 h0, l0, h1, l1;
            split8(t, h0, l0);
            split8(t + 8, h1, l1);
            *(u16x8*)(sm[0] + f) = h0; *(u16x8*)(sm[0] + f + 8) = h1;
            *(u16x8*)(sm[1] + f) = l0; *(u16x8*)(sm[1] + f + 8) = l1;
        }
        {
            size_t off = (size_t)(n0 + r) * 1024 + kt + c;
            float t[16];
            *(float4*)(t + 0)  = *(const float4*)(Bg + off);
            *(float4*)(t + 4)  = *(const float4*)(Bg + off + 4);
            *(float4*)(t + 8)  = *(const float4*)(Bg + off + 8);
            *(float4*)(t + 12) = *(const float4*)(Bg + off + 12);
            u16x8 h0, l0, h1, l1;
            split8(t, h0, l0);
            split8(t + 8, h1, l1);
            *(u16x8*)(sm[2] + f) = h0; *(u16x8*)(sm[2] + f + 8) = h1;
            *(u16x8*)(sm[3] + f) = l0; *(u16x8*)(sm[3] + f + 8) = l1;
        }
        __syncthreads();
        bf16x8 ah[4], al[4], bh[4], bl[4];
#pragma unroll
        for (int m = 0; m < 4; m++) {
            int row = wr * 64 + m * 16 + l15;
            ah[m] = *(const bf16x8*)(sm[0] + row * 32 + 8 * lhi);
            al[m] = *(const bf16x8*)(sm[1] + row * 32 + 8 * lhi);
        }
#pragma unroll
        for (int n = 0; n < 4; n++) {
            int row = wc * 64 + n * 16 + l15;
            bh[n] = *(const bf16x8*)(sm[2] + row * 32 + 8 * lhi);
            bl[n] = *(const bf16x8*)(sm[3] + row * 32 + 8 * lhi);
        }
#pragma unroll
        for (int m = 0; m < 4; m++)
#pragma unroll
            for (int n = 0; n < 4; n++) {
                acc[m][n] = __builtin_amdgcn_mfma_f32_16x16x32_bf16(al[m], bh[n], acc[m][n], 0, 0, 0);
                acc[m][n] = __builtin_amdgcn_mfma_f32_16x16x32_bf16(ah[m], bl[n], acc[m][n], 0, 0, 0);
                acc[m][n] = __builtin_amdgcn_mfma_f32_16x16x32_bf16(ah[m], bh[n], acc[m][n], 0, 0, 0);
            }
        __syncthreads();
    }

    if (z == 2) {
#pragma unroll
        for (int m = 0; m < 4; m++)
#pragma unroll
            for (int n = 0; n < 4; n++)
#pragma unroll
                for (int j = 0; j < 4; j++) {
                    int srow = m0 + wr * 64 + m * 16 + lhi * 4 + j;
                    int eg = n0 + wc * 64 + n * 16 + l15;
                    vtb[(size_t)eg * S_LEN + srow] = f2bf(acc[m][n][j]);
                }
        return;
    }

    u16* outp = (z == 0) ? q2 : k2;
    const float qscale = (z == 0) ? 0.125f : 1.0f;   // fold 1/sqrt(64) into Q (exact pow2)
    const int head = (n0 + wc * 64) >> 6;
#pragma unroll
    for (int m = 0; m < 4; m++)
#pragma unroll
        for (int n = 0; n < 4; n++) {
            const int dh = n * 16 + l15;
            const int pairi = dh >> 1;
            const bool even = (dh & 1) == 0;
#pragma unroll
            for (int j = 0; j < 4; j++) {
                int srow = m0 + wr * 64 + m * 16 + lhi * 4 + j;
                float v = acc[m][n][j];
                float pv = __shfl_xor(v, 1);
                int pos = tp[srow];
                float cc = cost[(size_t)pos * 32 + pairi];
                float ss = sint[(size_t)pos * 32 + pairi];
                float e = even ? v : pv;
                float o = even ? pv : v;
                float res = (even ? (e * cc - o * ss) : (e * ss + o * cc)) * qscale;
                u16 hb = f2bf(res);
                u16 lb = f2bf(res - bf2f(hb));
                size_t base = ((size_t)head * S_LEN + srow) * 128 + dh;
                outp[base] = hb;
                outp[base + 64] = lb;
            }
        }
}

// ---------------- Flash attention, swapped QK^T (S^T in registers) ----------------
// Q2 (pre-scaled 1/8) / K2: [h][s][128] bf16 = [hi|lo]. V^T: [h*64+d][s].
// grid (32,16); 4 waves; wave owns 32 q rows (2 groups of 16). KVBLK=64.
// S^T = mfma(K_frag, Q_frag): lane holds 16 k-scores for ONE q row per group ->
// softmax reduction = in-register tree + 2 shuffles (xor16, xor32), not 64 bpermutes.
// O accumulated transposed: O^T = mfma(VT_frag, P_frag).
#define PLD32 33   // P LDS row stride in u32 (32 q rows x 66 u16)
__global__ __launch_bounds__(256) void attn_kernel(const u16* __restrict__ q2,
                                                   const u16* __restrict__ k2,
                                                   const u16* __restrict__ vtb,
                                                   u16* __restrict__ attnb) {
    const int h = blockIdx.y;
    const int qblk = gridDim.x - 1 - blockIdx.x;   // big tiles launch first
    const int wid = threadIdx.x >> 6;
    const int lane = threadIdx.x & 63;
    const int l15 = lane & 15, lhi = lane >> 4;
    const int q0 = qblk * 128 + wid * 32;          // wave's 32-row base

    const u16* Qh2 = q2 + (size_t)h * S_LEN * 128;
    const u16* Kh2 = k2 + (size_t)h * S_LEN * 128;
    const u16* Vh = vtb + (size_t)h * 64 * S_LEN;

    __shared__ unsigned pls[4][32 * PLD32];
    unsigned* myP = pls[wid];

    // Q fragments (B-frags now): row = q0+g*16+l15, d = ks*32 + 8*lhi (+0 hi, +64 lo)
    bf16x8 qhf[2][2], qlf[2][2];
#pragma unroll
    for (int g = 0; g < 2; g++)
#pragma unroll
        for (int ks = 0; ks < 2; ks++) {
            const u16* qp = Qh2 + (size_t)(q0 + g * 16 + l15) * 128 + ks * 32 + 8 * lhi;
            qhf[g][ks] = *(const bf16x8*)(qp);
            qlf[g][ks] = *(const bf16x8*)(qp + 64);
        }

    f32x4 oT[2][4];   // [g][d-subtile]; lane: q = g*16+l15, d = dsub*16 + lhi*4 + j
#pragma unroll
    for (int g = 0; g < 2; g++)
#pragma unroll
        for (int m = 0; m < 4; m++) oT[g][m] = (f32x4){0.f, 0.f, 0.f, 0.f};
    float m_run[2] = {-1e30f, -1e30f};
    float l_run[2] = {0.f, 0.f};

    const int nkb = ((q0 + 31) >> 6) + 1;
    for (int kblk = 0; kblk < nkb; kblk++) {
        const int k0 = kblk * 64;
        // K fragments (A-frags): row = k0+m*16+l15, d = 8*lhi (+32 chunk), hi/lo
        bf16x8 kh[4][2], kl[4][2];
#pragma unroll
        for (int m = 0; m < 4; m++) {
            const u16* kp = Kh2 + (size_t)(k0 + m * 16 + l15) * 128 + 8 * lhi;
            kh[m][0] = *(const bf16x8*)(kp);
            kh[m][1] = *(const bf16x8*)(kp + 32);
            kl[m][0] = *(const bf16x8*)(kp + 64);
            kl[m][1] = *(const bf16x8*)(kp + 96);
        }
        // S^T tiles: sT[m][g][j] = score(k = k0+m*16+lhi*4+j, q = q0+g*16+l15)
        f32x4 sT[4][2];
#pragma unroll
        for (int m = 0; m < 4; m++)
#pragma unroll
            for (int g = 0; g < 2; g++) {
                f32x4 a = (f32x4){0.f, 0.f, 0.f, 0.f};
                a = __builtin_amdgcn_mfma_f32_16x16x32_bf16(kh[m][0], qlf[g][0], a, 0, 0, 0);
                a = __builtin_amdgcn_mfma_f32_16x16x32_bf16(kh[m][1], qlf[g][1], a, 0, 0, 0);
                a = __builtin_amdgcn_mfma_f32_16x16x32_bf16(kl[m][0], qhf[g][0], a, 0, 0, 0);
                a = __builtin_amdgcn_mfma_f32_16x16x32_bf16(kl[m][1], qhf[g][1], a, 0, 0, 0);
                a = __builtin_amdgcn_mfma_f32_16x16x32_bf16(kh[m][0], qhf[g][0], a, 0, 0, 0);
                a = __builtin_amdgcn_mfma_f32_16x16x32_bf16(kh[m][1], qhf[g][1], a, 0, 0, 0);
                sT[m][g] = a;
            }
        // V^T fragments issued now -> latency hides under softmax
        bf16x8 vf[4][2];
#pragma unroll
        for (int m = 0; m < 4; m++) {
            const u16* vp = Vh + (size_t)(m * 16 + l15) * S_LEN + k0 + 8 * lhi;
            vf[m][0] = *(const bf16x8*)(vp);
            vf[m][1] = *(const bf16x8*)(vp + 32);
        }
        const bool last = (kblk == nkb - 1);
        // online softmax per group: in-register over 16 k-values + 2 cross-lane shuffles
#pragma unroll
        for (int g = 0; g < 2; g++) {
            const int qg = q0 + g * 16 + l15;
            if (last) {
#pragma unroll
                for (int m = 0; m < 4; m++)
#pragma unroll
                    for (int j = 0; j < 4; j++) {
                        int kg = k0 + m * 16 + lhi * 4 + j;
                        if (kg > qg) sT[m][g][j] = -1e30f;
                    }
            }
            // max tree over 16 regs
            float t0 = fmaxf(fmaxf(sT[0][g][0], sT[0][g][1]), fmaxf(sT[0][g][2], sT[0][g][3]));
            float t1 = fmaxf(fmaxf(sT[1][g][0], sT[1][g][1]), fmaxf(sT[1][g][2], sT[1][g][3]));
            float t2 = fmaxf(fmaxf(sT[2][g][0], sT[2][g][1]), fmaxf(sT[2][g][2], sT[2][g][3]));
            float t3 = fmaxf(fmaxf(sT[3][g][0], sT[3][g][1]), fmaxf(sT[3][g][2], sT[3][g][3]));
            float mx = fmaxf(fmaxf(t0, t1), fmaxf(t2, t3));
            mx = fmaxf(mx, __shfl_xor(mx, 16));
            mx = fmaxf(mx, __shfl_xor(mx, 32));
            float mn = fmaxf(m_run[g], mx);
            float alpha = __expf(m_run[g] - mn);
            float s0 = 0.f, s1 = 0.f, s2 = 0.f, s3 = 0.f;
#pragma unroll
            for (int m = 0; m < 4; m++) {
                float p0 = __expf(sT[m][g][0] - mn);
                float p1 = __expf(sT[m][g][1] - mn);
                float p2 = __expf(sT[m][g][2] - mn);
                float p3 = __expf(sT[m][g][3] - mn);
                sT[m][g][0] = p0; sT[m][g][1] = p1; sT[m][g][2] = p2; sT[m][g][3] = p3;
                s0 += p0; s1 += p1; s2 += p2; s3 += p3;
            }
            float rs = (s0 + s1) + (s2 + s3);
            rs += __shfl_xor(rs, 16);
            rs += __shfl_xor(rs, 32);
            l_run[g] = l_run[g] * alpha + rs;
            m_run[g] = mn;
#pragma unroll
            for (int m = 0; m < 4; m++) {
                oT[g][m][0] *= alpha; oT[g][m][1] *= alpha;
                oT[g][m][2] *= alpha; oT[g][m][3] *= alpha;
            }
            // store P^T value at [q = g*16+l15][k], packed u32 (j-pairs are adjacent k)
#pragma unroll
            for (int m = 0; m < 4; m++)
#pragma unroll
                for (int jj = 0; jj < 2; jj++) {
                    unsigned pk = (unsigned)f2bf(sT[m][g][2 * jj]) |
                                  ((unsigned)f2bf(sT[m][g][2 * jj + 1]) << 16);
                    myP[(g * 16 + l15) * PLD32 + m * 8 + lhi * 2 + jj] = pk;
                }
        }
        // P B-frags: row = q (g*16+l15), k = ks*32 + 8*lhi (u32 idx: ks*16 + 4*lhi)
        bf16x8 pf[2][2];
#pragma unroll
        for (int g = 0; g < 2; g++)
#pragma unroll
            for (int ks = 0; ks < 2; ks++) {
                uint4v pw = *(const uint4v*)(myP + (g * 16 + l15) * PLD32 + ks * 16 + 4 * lhi);
                pf[g][ks] = __builtin_bit_cast(bf16x8, pw);
            }
        // O^T += V^T P : oT[g][m] covers d = m*16+lhi*4+j for q = g*16+l15
#pragma unroll
        for (int g = 0; g < 2; g++)
#pragma unroll
            for (int m = 0; m < 4; m++) {
                oT[g][m] = __builtin_amdgcn_mfma_f32_16x16x32_bf16(vf[m][0], pf[g][0], oT[g][m], 0, 0, 0);
                oT[g][m] = __builtin_amdgcn_mfma_f32_16x16x32_bf16(vf[m][1], pf[g][1], oT[g][m], 0, 0, 0);
            }
    }
    // epilogue: O[q][d] = oT / l ; scattered u16 stores (once per wave)
#pragma unroll
    for (int g = 0; g < 2; g++) {
        const int srow = q0 + g * 16 + l15;
#pragma unroll
        for (int m = 0; m < 4; m++)
#pragma unroll
            for (int j = 0; j < 4; j++) {
                float v = oT[g][m][j] / l_run[g];
                attnb[(size_t)srow * 1024 + h * 64 + m * 16 + lhi * 4 + j] = f2bf(v);
            }
    }
}

// ---------------- output projection: attn bf16 x (w_o fp32 -> bf16)^T -> fp32 ----------------
__global__ __launch_bounds__(256) void gemm_out_kernel(const u16* __restrict__ attnb,
                                                       const float* __restrict__ wo,
                                                       float* __restrict__ out) {
    __shared__ u16 sA[128 * 32];
    __shared__ u16 sB[128 * 32];
    const int m0 = blockIdx.y * 128, n0 = blockIdx.x * 128;
    const int tid = threadIdx.x;
    const int lane = tid & 63, wid = tid >> 6;
    const int wr = wid >> 1, wc = wid & 1;
    const int l15 = lane & 15, lhi = lane >> 4;

    f32x4 acc[4][4];
#pragma unroll
    for (int i = 0; i < 4; i++)
#pragma unroll
        for (int j = 0; j < 4; j++) acc[i][j] = (f32x4){0.f, 0.f, 0.f, 0.f};

    const int f = tid * 16;
    const int r = f >> 5, c = f & 31;

    for (int kt = 0; kt < 1024; kt += 32) {
        *(bf16x8*)(sA + f)     = *(const bf16x8*)(attnb + (size_t)(m0 + r) * 1024 + kt + c);
        *(bf16x8*)(sA + f + 8) = *(const bf16x8*)(attnb + (size_t)(m0 + r) * 1024 + kt + c + 8);
        {
            size_t off = (size_t)(n0 + r) * 1024 + kt + c;
            float t[16];
            *(float4*)(t + 0)  = *(const float4*)(wo + off);
            *(float4*)(t + 4)  = *(const float4*)(wo + off + 4);
            *(float4*)(t + 8)  = *(const float4*)(wo + off + 8);
            *(float4*)(t + 12) = *(const float4*)(wo + off + 12);
            u16x8 h0, h1;
#pragma unroll
            for (int i = 0; i < 8; i++) h0[i] = f2bf(t[i]);
#pragma unroll
            for (int i = 0; i < 8; i++) h1[i] = f2bf(t[8 + i]);
            *(u16x8*)(sB + f) = h0;
            *(u16x8*)(sB + f + 8) = h1;
        }
        __syncthreads();
        bf16x8 af[4], bfr[4];
#pragma unroll
        for (int m = 0; m < 4; m++) {
            int row = wr * 64 + m * 16 + l15;
            af[m] = *(const bf16x8*)(sA + row * 32 + 8 * lhi);
        }
#pragma unroll
        for (int n = 0; n < 4; n++) {
            int row = wc * 64 + n * 16 + l15;
            bfr[n] = *(const bf16x8*)(sB + row * 32 + 8 * lhi);
        }
#pragma unroll
        for (int m = 0; m < 4; m++)
#pragma unroll
            for (int n = 0; n < 4; n++)
                acc[m][n] = __builtin_amdgcn_mfma_f32_16x16x32_bf16(af[m], bfr[n], acc[m][n], 0, 0, 0);
        __syncthreads();
    }

#pragma unroll
    for (int m = 0; m < 4; m++)
#pragma unroll
        for (int n = 0; n < 4; n++)
#pragma unroll
            for (int j = 0; j < 4; j++) {
                int srow = m0 + wr * 64 + m * 16 + lhi * 4 + j;
                int eg = n0 + wc * 64 + n * 16 + l15;
                out[(size_t)srow * 1024 + eg] = acc[m][n][j];
            }
}

// ---------------- host launch ----------------
extern "C" void kernel_launch(void* const* d_in, const int* in_sizes, int n_in,
                              void* d_out, int out_size, void* d_ws, size_t ws_size,
                              hipStream_t stream) {
    const float* x = (const float*)d_in[0];
    const int* tp = (const int*)d_in[1];
    const float* wq = (const float*)d_in[2];
    const float* wk = (const float*)d_in[3];
    const float* wv = (const float*)d_in[4];
    const float* wo = (const float*)d_in[5];
    float* out = (float*)d_out;
    char* ws = (char*)d_ws;

    u16* Q2    = (u16*)(ws + 0);           // 16 MiB bf16 [16][4096][128] hi/lo, pre-scaled 1/8
    u16* K2    = (u16*)(ws + 16777216);    // 16 MiB
    u16* VTB   = (u16*)(ws + 33554432);    // 8 MiB bf16 [h*64+dh][4096]
    u16* ATTNB = (u16*)(ws + 41943040);    // 8 MiB bf16 [4096][1024]
    float* COST = (float*)(ws + 50331648); // 512 KiB
    float* SINT = (float*)(ws + 50855936); // 512 KiB

    rope_table_kernel<<<512, 256, 0, stream>>>(COST, SINT);

    gemm_qkv_split_kernel<<<dim3(8, 32, 3), 256, 0, stream>>>(
        x, wq, wk, wv, tp, COST, SINT, Q2, K2, VTB);

    attn_kernel<<<dim3(32, 16), 256, 0, stream>>>(Q2, K2, VTB, ATTNB);

    gemm_out_kernel<<<dim3(8, 32), 256, 0, stream>>>(ATTNB, wo, out);
}

// Round 6
// 419.099 us; speedup vs baseline: 2.1832x; 1.3846x over previous
//
#include <hip/hip_runtime.h>
#include <math.h>

#define S_LEN 4096
#define DMODEL 1024
#define NHEADS 16
#define DHEAD 64

typedef unsigned short u16;
typedef short bf16x8 __attribute__((ext_vector_type(8)));
typedef float f32x4 __attribute__((ext_vector_type(4)));
typedef u16 u16x8 __attribute__((ext_vector_type(8)));
typedef unsigned uint4v __attribute__((ext_vector_type(4)));

__device__ __forceinline__ u16 f2bf(float f) {
    unsigned u = __builtin_bit_cast(unsigned, f);
    u = (u + 0x7FFFu + ((u >> 16) & 1u)) >> 16;
    return (u16)u;
}
__device__ __forceinline__ float bf2f(u16 b) {
    return __builtin_bit_cast(float, ((unsigned)b) << 16);
}

// async global->LDS, 16B per lane; LDS dest is wave-uniform base + lane*16
__device__ __forceinline__ void gload16(const void* g, void* l) {
    __builtin_amdgcn_global_load_lds((const __attribute__((address_space(1))) void*)g,
                                     (__attribute__((address_space(3))) void*)l, 16, 0, 0);
}

// ---------------- RoPE tables (fp32-faithful to numpy float32 path) ----------------
__global__ void rope_table_kernel(float* __restrict__ cost, float* __restrict__ sint) {
    int tid = blockIdx.x * blockDim.x + threadIdx.x;  // 4096*32
    int i = tid & 31;
    int pos = tid >> 5;
    double e = (double)(2 * i) / 64.0;
    float t32 = (float)pow(10000.0, e);
    float freq = 1.0f / t32;
    float ang = (float)pos * freq;
    cost[tid] = (float)cos((double)ang);
    sint[tid] = (float)sin((double)ang);
}

// split 8 fp32 -> hi/lo bf16
__device__ __forceinline__ void split8(const float* v, u16x8& h, u16x8& l) {
#pragma unroll
    for (int i = 0; i < 8; i++) {
        u16 hh = f2bf(v[i]);
        h[i] = hh;
        l[i] = f2bf(v[i] - bf2f(hh));
    }
}

// ---------------- split-GEMM QKV + fused RoPE ----------------
// z=0 -> Q2 bf16 hi/lo [h][s][128] (RoPE applied, pre-scaled by 1/8),
// z=1 -> K2 same (unscaled), z=2 -> V^T bf16 [h*64+dh][s].
__global__ __launch_bounds__(256) void gemm_qkv_split_kernel(
        const float* __restrict__ x,
        const float* __restrict__ wq, const float* __restrict__ wk, const float* __restrict__ wv,
        const int* __restrict__ tp,
        const float* __restrict__ cost, const float* __restrict__ sint,
        u16* __restrict__ q2, u16* __restrict__ k2, u16* __restrict__ vtb) {
    __shared__ u16 sm[4][128 * 32];   // AH, AL, BH, BL
    const int z = blockIdx.z;
    const float* Bg = (z == 0) ? wq : (z == 1) ? wk : wv;
    const int m0 = blockIdx.y * 128, n0 = blockIdx.x * 128;

    const int tid = threadIdx.x;
    const int lane = tid & 63, wid = tid >> 6;
    const int wr = wid >> 1, wc = wid & 1;
    const int l15 = lane & 15, lhi = lane >> 4;

    f32x4 acc[4][4];
#pragma unroll
    for (int i = 0; i < 4; i++)
#pragma unroll
        for (int j = 0; j < 4; j++) acc[i][j] = (f32x4){0.f, 0.f, 0.f, 0.f};

    const int f = tid * 16;
    const int r = f >> 5, c = f & 31;

    for (int kt = 0; kt < 1024; kt += 32) {
        {
            size_t off = (size_t)(m0 + r) * 1024 + kt + c;
            float t[16];
            *(float4*)(t + 0)  = *(const float4*)(x + off);
            *(float4*)(t + 4)  = *(const float4*)(x + off + 4);
            *(float4*)(t + 8)  = *(const float4*)(x + off + 8);
            *(float4*)(t + 12) = *(const float4*)(x + off + 12);
            u16x8 h0, l0, h1, l1;
            split8(t, h0, l0);
            split8(t + 8, h1, l1);
            *(u16x8*)(sm[0] + f) = h0; *(u16x8*)(sm[0] + f + 8) = h1;
            *(u16x8*)(sm[1] + f) = l0; *(u16x8*)(sm[1] + f + 8) = l1;
        }
        {
            size_t off = (size_t)(n0 + r) * 1024 + kt + c;
            float t[16];
            *(float4*)(t + 0)  = *(const float4*)(Bg + off);
            *(float4*)(t + 4)  = *(const float4*)(Bg + off + 4);
            *(float4*)(t + 8)  = *(const float4*)(Bg + off + 8);
            *(float4*)(t + 12) = *(const float4*)(Bg + off + 12);
            u16x8 h0, l0, h1, l1;
            split8(t, h0, l0);
            split8(t + 8, h1, l1);
            *(u16x8*)(sm[2] + f) = h0; *(u16x8*)(sm[2] + f + 8) = h1;
            *(u16x8*)(sm[3] + f) = l0; *(u16x8*)(sm[3] + f + 8) = l1;
        }
        __syncthreads();
        bf16x8 ah[4], al[4], bh[4], bl[4];
#pragma unroll
        for (int m = 0; m < 4; m++) {
            int row = wr * 64 + m * 16 + l15;
            ah[m] = *(const bf16x8*)(sm[0] + row * 32 + 8 * lhi);
            al[m] = *(const bf16x8*)(sm[1] + row * 32 + 8 * lhi);
        }
#pragma unroll
        for (int n = 0; n < 4; n++) {
            int row = wc * 64 + n * 16 + l15;
            bh[n] = *(const bf16x8*)(sm[2] + row * 32 + 8 * lhi);
            bl[n] = *(const bf16x8*)(sm[3] + row * 32 + 8 * lhi);
        }
#pragma unroll
        for (int m = 0; m < 4; m++)
#pragma unroll
            for (int n = 0; n < 4; n++) {
                acc[m][n] = __builtin_amdgcn_mfma_f32_16x16x32_bf16(al[m], bh[n], acc[m][n], 0, 0, 0);
                acc[m][n] = __builtin_amdgcn_mfma_f32_16x16x32_bf16(ah[m], bl[n], acc[m][n], 0, 0, 0);
                acc[m][n] = __builtin_amdgcn_mfma_f32_16x16x32_bf16(ah[m], bh[n], acc[m][n], 0, 0, 0);
            }
        __syncthreads();
    }

    if (z == 2) {
#pragma unroll
        for (int m = 0; m < 4; m++)
#pragma unroll
            for (int n = 0; n < 4; n++)
#pragma unroll
                for (int j = 0; j < 4; j++) {
                    int srow = m0 + wr * 64 + m * 16 + lhi * 4 + j;
                    int eg = n0 + wc * 64 + n * 16 + l15;
                    vtb[(size_t)eg * S_LEN + srow] = f2bf(acc[m][n][j]);
                }
        return;
    }

    u16* outp = (z == 0) ? q2 : k2;
    const float qscale = (z == 0) ? 0.125f : 1.0f;   // fold 1/sqrt(64) into Q (exact pow2)
    const int head = (n0 + wc * 64) >> 6;
#pragma unroll
    for (int m = 0; m < 4; m++)
#pragma unroll
        for (int n = 0; n < 4; n++) {
            const int dh = n * 16 + l15;
            const int pairi = dh >> 1;
            const bool even = (dh & 1) == 0;
#pragma unroll
            for (int j = 0; j < 4; j++) {
                int srow = m0 + wr * 64 + m * 16 + lhi * 4 + j;
                float v = acc[m][n][j];
                float pv = __shfl_xor(v, 1);
                int pos = tp[srow];
                float cc = cost[(size_t)pos * 32 + pairi];
                float ss = sint[(size_t)pos * 32 + pairi];
                float e = even ? v : pv;
                float o = even ? pv : v;
                float res = (even ? (e * cc - o * ss) : (e * ss + o * cc)) * qscale;
                u16 hb = f2bf(res);
                u16 lb = f2bf(res - bf2f(hb));
                size_t base = ((size_t)head * S_LEN + srow) * 128 + dh;
                outp[base] = hb;
                outp[base + 64] = lb;
            }
        }
}

// ---------------- Flash attention: paired q-tiles + LDS-staged K/V double buffer ----------------
// Q2 (pre-scaled 1/8) / K2: [h][s][128] bf16 = [hi|lo]. V^T: [h*64+d][s].
// grid (16 pairs, 16 heads); 4 waves x 32 q rows = 128-row tile; block does tiles (31-p, p)
// sequentially -> uniform 66 kv-steps per block. K/V staged via global_load_lds with
// XOR swizzle (byte ^= (row&7)<<4) applied identically on pre-swizzled source and ds_read.
#define PLD32 33
__global__ __launch_bounds__(256) void attn_kernel(const u16* __restrict__ q2,
                                                   const u16* __restrict__ k2,
                                                   const u16* __restrict__ vtb,
                                                   u16* __restrict__ attnb) {
    const int h = blockIdx.y;
    const int p = blockIdx.x;              // pair id 0..15 -> tiles (31-p, p)
    const int wid = threadIdx.x >> 6;
    const int lane = threadIdx.x & 63;
    const int l15 = lane & 15, lhi = lane >> 4;

    const u16* Qh2 = q2 + (size_t)h * S_LEN * 128;
    const u16* Kh2 = k2 + (size_t)h * S_LEN * 128;
    const u16* Vh  = vtb + (size_t)h * 64 * S_LEN;

    __shared__ u16 sK[2][64 * 128];        // 64 kv rows x (hi|lo) 128, swizzled
    __shared__ u16 sV[2][64 * 64];         // 64 d rows x 64 kv cols, swizzled
    __shared__ unsigned pls[4][32 * PLD32];
    unsigned* myP = pls[wid];

    const int tileA = 31 - p, tileB = p;
    const int eA = 2 * tileA + 2, eB = 2 * tileB + 2;
    const int etot = eA + eB;              // 66 for every block

    auto stage = [&](int t, int b) {
        const int k = (t < eA) ? t : (t - eA);
        const int k0 = k * 64;
        // K tile: wave stages rows [wid*16, wid*16+16): 4 loads x 4 rows (1KB each)
#pragma unroll
        for (int i = 0; i < 4; i++) {
            const int rbase = wid * 16 + i * 4;
            const int row = rbase + (lane >> 4);
            const int cb = (lane & 15) * 16;                 // byte col in 256B row
            const int csw = cb ^ ((row & 7) << 4);           // pre-swizzled source col
            gload16(Kh2 + (size_t)(k0 + row) * 128 + (csw >> 1), &sK[b][rbase * 128]);
        }
        // V tile: wave stages d-rows [wid*16, wid*16+16): 2 loads x 8 rows (128B each)
#pragma unroll
        for (int i = 0; i < 2; i++) {
            const int rbase = wid * 16 + i * 8;
            const int row = rbase + (lane >> 3);
            const int cb = (lane & 7) * 16;                  // byte col in 128B row
            const int csw = cb ^ ((row & 7) << 4);
            gload16(Vh + (size_t)row * S_LEN + k0 + (csw >> 1), &sV[b][rbase * 64]);
        }
    };

    bf16x8 qhf[2][2], qlf[2][2];
    f32x4 oT[2][4];
    float m_run[2], l_run[2];
    int q0 = 0, my_nkb = 0;

    auto initPass = [&](int tile) {
        q0 = tile * 128 + wid * 32;
        my_nkb = ((q0 + 31) >> 6) + 1;
#pragma unroll
        for (int g = 0; g < 2; g++)
#pragma unroll
            for (int ks = 0; ks < 2; ks++) {
                const u16* qp = Qh2 + (size_t)(q0 + g * 16 + l15) * 128 + ks * 32 + 8 * lhi;
                qhf[g][ks] = *(const bf16x8*)(qp);
                qlf[g][ks] = *(const bf16x8*)(qp + 64);
            }
#pragma unroll
        for (int g = 0; g < 2; g++) {
            m_run[g] = -1e30f;
            l_run[g] = 0.f;
#pragma unroll
            for (int m = 0; m < 4; m++) oT[g][m] = (f32x4){0.f, 0.f, 0.f, 0.f};
        }
    };

    auto writeOut = [&]() {
#pragma unroll
        for (int g = 0; g < 2; g++) {
            const int srow = q0 + g * 16 + l15;
            const float inv = 1.0f / l_run[g];
#pragma unroll
            for (int m = 0; m < 4; m++)
#pragma unroll
                for (int j = 0; j < 4; j++)
                    attnb[(size_t)srow * 1024 + h * 64 + m * 16 + lhi * 4 + j] =
                        f2bf(oT[g][m][j] * inv);
        }
    };

    stage(0, 0);
    initPass(tileA);
    __syncthreads();   // drains vmcnt(0): buf0 ready

    int cur = 0;
    for (int t = 0; t < etot; ++t) {
        if (t + 1 < etot) stage(t + 1, cur ^ 1);    // prefetch next tile
        if (t == eA) { writeOut(); initPass(tileB); }
        const int k = (t < eA) ? t : (t - eA);
        if (k < my_nkb) {
            const int k0 = k * 64;
            // ---- LDS reads (swizzled) ----
            bf16x8 kh[4][2], kl[4][2], vfr[4][2];
#pragma unroll
            for (int m = 0; m < 4; m++) {
                const int r = m * 16 + l15;
                const int sw = (r & 7) << 4;
                const u16* kp = &sK[cur][r * 128];
                const u16* vp = &sV[cur][r * 64];
#pragma unroll
                for (int c = 0; c < 2; c++) {
                    kh[m][c] = *(const bf16x8*)(kp + (((c * 64 + lhi * 16) ^ sw) >> 1));
                    kl[m][c] = *(const bf16x8*)(kp + (((128 + c * 64 + lhi * 16) ^ sw) >> 1));
                    vfr[m][c] = *(const bf16x8*)(vp + (((c * 64 + lhi * 16) ^ sw) >> 1));
                }
            }
            // ---- S^T = K Q^T (bf16x3) ----
            f32x4 sT[4][2];
#pragma unroll
            for (int m = 0; m < 4; m++)
#pragma unroll
                for (int g = 0; g < 2; g++) {
                    f32x4 a = (f32x4){0.f, 0.f, 0.f, 0.f};
                    a = __builtin_amdgcn_mfma_f32_16x16x32_bf16(kh[m][0], qlf[g][0], a, 0, 0, 0);
                    a = __builtin_amdgcn_mfma_f32_16x16x32_bf16(kh[m][1], qlf[g][1], a, 0, 0, 0);
                    a = __builtin_amdgcn_mfma_f32_16x16x32_bf16(kl[m][0], qhf[g][0], a, 0, 0, 0);
                    a = __builtin_amdgcn_mfma_f32_16x16x32_bf16(kl[m][1], qhf[g][1], a, 0, 0, 0);
                    a = __builtin_amdgcn_mfma_f32_16x16x32_bf16(kh[m][0], qhf[g][0], a, 0, 0, 0);
                    a = __builtin_amdgcn_mfma_f32_16x16x32_bf16(kh[m][1], qhf[g][1], a, 0, 0, 0);
                    sT[m][g] = a;
                }
            const bool last = (k == my_nkb - 1);
            // ---- online softmax (in-register over 16 k + 2 shuffles) ----
#pragma unroll
            for (int g = 0; g < 2; g++) {
                const int qg = q0 + g * 16 + l15;
                if (last) {
#pragma unroll
                    for (int m = 0; m < 4; m++)
#pragma unroll
                        for (int j = 0; j < 4; j++) {
                            int kg = k0 + m * 16 + lhi * 4 + j;
                            if (kg > qg) sT[m][g][j] = -1e30f;
                        }
                }
                float t0 = fmaxf(fmaxf(sT[0][g][0], sT[0][g][1]), fmaxf(sT[0][g][2], sT[0][g][3]));
                float t1 = fmaxf(fmaxf(sT[1][g][0], sT[1][g][1]), fmaxf(sT[1][g][2], sT[1][g][3]));
                float t2 = fmaxf(fmaxf(sT[2][g][0], sT[2][g][1]), fmaxf(sT[2][g][2], sT[2][g][3]));
                float t3 = fmaxf(fmaxf(sT[3][g][0], sT[3][g][1]), fmaxf(sT[3][g][2], sT[3][g][3]));
                float mx = fmaxf(fmaxf(t0, t1), fmaxf(t2, t3));
                mx = fmaxf(mx, __shfl_xor(mx, 16));
                mx = fmaxf(mx, __shfl_xor(mx, 32));
                float mn = fmaxf(m_run[g], mx);
                float alpha = __expf(m_run[g] - mn);
                float s0 = 0.f, s1 = 0.f, s2 = 0.f, s3 = 0.f;
#pragma unroll
                for (int m = 0; m < 4; m++) {
                    float p0 = __expf(sT[m][g][0] - mn);
                    float p1 = __expf(sT[m][g][1] - mn);
                    float p2 = __expf(sT[m][g][2] - mn);
                    float p3 = __expf(sT[m][g][3] - mn);
                    sT[m][g][0] = p0; sT[m][g][1] = p1; sT[m][g][2] = p2; sT[m][g][3] = p3;
                    s0 += p0; s1 += p1; s2 += p2; s3 += p3;
                }
                float rs = (s0 + s1) + (s2 + s3);
                rs += __shfl_xor(rs, 16);
                rs += __shfl_xor(rs, 32);
                l_run[g] = l_run[g] * alpha + rs;
                m_run[g] = mn;
#pragma unroll
                for (int m = 0; m < 4; m++) {
                    oT[g][m][0] *= alpha; oT[g][m][1] *= alpha;
                    oT[g][m][2] *= alpha; oT[g][m][3] *= alpha;
                }
#pragma unroll
                for (int m = 0; m < 4; m++)
#pragma unroll
                    for (int jj = 0; jj < 2; jj++) {
                        unsigned pk = (unsigned)f2bf(sT[m][g][2 * jj]) |
                                      ((unsigned)f2bf(sT[m][g][2 * jj + 1]) << 16);
                        myP[(g * 16 + l15) * PLD32 + m * 8 + lhi * 2 + jj] = pk;
                    }
            }
            // ---- P B-frags from per-wave LDS ----
            bf16x8 pf[2][2];
#pragma unroll
            for (int g = 0; g < 2; g++)
#pragma unroll
                for (int ks = 0; ks < 2; ks++) {
                    uint4v pw = *(const uint4v*)(myP + (g * 16 + l15) * PLD32 + ks * 16 + 4 * lhi);
                    pf[g][ks] = __builtin_bit_cast(bf16x8, pw);
                }
            // ---- O^T += V^T P ----
#pragma unroll
            for (int g = 0; g < 2; g++)
#pragma unroll
                for (int m = 0; m < 4; m++) {
                    oT[g][m] = __builtin_amdgcn_mfma_f32_16x16x32_bf16(vfr[m][0], pf[g][0], oT[g][m], 0, 0, 0);
                    oT[g][m] = __builtin_amdgcn_mfma_f32_16x16x32_bf16(vfr[m][1], pf[g][1], oT[g][m], 0, 0, 0);
                }
        }
        __syncthreads();   // drains vmcnt(0): next buffer staged, this buffer free
        cur ^= 1;
    }
    writeOut();
}

// ---------------- output projection: attn bf16 x (w_o fp32 -> bf16)^T -> fp32 ----------------
__global__ __launch_bounds__(256) void gemm_out_kernel(const u16* __restrict__ attnb,
                                                       const float* __restrict__ wo,
                                                       float* __restrict__ out) {
    __shared__ u16 sA[128 * 32];
    __shared__ u16 sB[128 * 32];
    const int m0 = blockIdx.y * 128, n0 = blockIdx.x * 128;
    const int tid = threadIdx.x;
    const int lane = tid & 63, wid = tid >> 6;
    const int wr = wid >> 1, wc = wid & 1;
    const int l15 = lane & 15, lhi = lane >> 4;

    f32x4 acc[4][4];
#pragma unroll
    for (int i = 0; i < 4; i++)
#pragma unroll
        for (int j = 0; j < 4; j++) acc[i][j] = (f32x4){0.f, 0.f, 0.f, 0.f};

    const int f = tid * 16;
    const int r = f >> 5, c = f & 31;

    for (int kt = 0; kt < 1024; kt += 32) {
        *(bf16x8*)(sA + f)     = *(const bf16x8*)(attnb + (size_t)(m0 + r) * 1024 + kt + c);
        *(bf16x8*)(sA + f + 8) = *(const bf16x8*)(attnb + (size_t)(m0 + r) * 1024 + kt + c + 8);
        {
            size_t off = (size_t)(n0 + r) * 1024 + kt + c;
            float t[16];
            *(float4*)(t + 0)  = *(const float4*)(wo + off);
            *(float4*)(t + 4)  = *(const float4*)(wo + off + 4);
            *(float4*)(t + 8)  = *(const float4*)(wo + off + 8);
            *(float4*)(t + 12) = *(const float4*)(wo + off + 12);
            u16x8 h0, h1;
#pragma unroll
            for (int i = 0; i < 8; i++) h0[i] = f2bf(t[i]);
#pragma unroll
            for (int i = 0; i < 8; i++) h1[i] = f2bf(t[8 + i]);
            *(u16x8*)(sB + f) = h0;
            *(u16x8*)(sB + f + 8) = h1;
        }
        __syncthreads();
        bf16x8 af[4], bfr[4];
#pragma unroll
        for (int m = 0; m < 4; m++) {
            int row = wr * 64 + m * 16 + l15;
            af[m] = *(const bf16x8*)(sA + row * 32 + 8 * lhi);
        }
#pragma unroll
        for (int n = 0; n < 4; n++) {
            int row = wc * 64 + n * 16 + l15;
            bfr[n] = *(const bf16x8*)(sB + row * 32 + 8 * lhi);
        }
#pragma unroll
        for (int m = 0; m < 4; m++)
#pragma unroll
            for (int n = 0; n < 4; n++)
                acc[m][n] = __builtin_amdgcn_mfma_f32_16x16x32_bf16(af[m], bfr[n], acc[m][n], 0, 0, 0);
        __syncthreads();
    }

#pragma unroll
    for (int m = 0; m < 4; m++)
#pragma unroll
        for (int n = 0; n < 4; n++)
#pragma unroll
            for (int j = 0; j < 4; j++) {
                int srow = m0 + wr * 64 + m * 16 + lhi * 4 + j;
                int eg = n0 + wc * 64 + n * 16 + l15;
                out[(size_t)srow * 1024 + eg] = acc[m][n][j];
            }
}

// ---------------- host launch ----------------
extern "C" void kernel_launch(void* const* d_in, const int* in_sizes, int n_in,
                              void* d_out, int out_size, void* d_ws, size_t ws_size,
                              hipStream_t stream) {
    const float* x = (const float*)d_in[0];
    const int* tp = (const int*)d_in[1];
    const float* wq = (const float*)d_in[2];
    const float* wk = (const float*)d_in[3];
    const float* wv = (const float*)d_in[4];
    const float* wo = (const float*)d_in[5];
    float* out = (float*)d_out;
    char* ws = (char*)d_ws;

    u16* Q2    = (u16*)(ws + 0);           // 16 MiB bf16 [16][4096][128] hi/lo, pre-scaled 1/8
    u16* K2    = (u16*)(ws + 16777216);    // 16 MiB
    u16* VTB   = (u16*)(ws + 33554432);    // 8 MiB bf16 [h*64+dh][4096]
    u16* ATTNB = (u16*)(ws + 41943040);    // 8 MiB bf16 [4096][1024]
    float* COST = (float*)(ws + 50331648); // 512 KiB
    float* SINT = (float*)(ws + 50855936); // 512 KiB

    rope_table_kernel<<<512, 256, 0, stream>>>(COST, SINT);

    gemm_qkv_split_kernel<<<dim3(8, 32, 3), 256, 0, stream>>>(
        x, wq, wk, wv, tp, COST, SINT, Q2, K2, VTB);

    attn_kernel<<<dim3(16, 16), 256, 0, stream>>>(Q2, K2, VTB, ATTNB);

    gemm_out_kernel<<<dim3(8, 32), 256, 0, stream>>>(ATTNB, wo, out);
}

// Round 7
// 364.425 us; speedup vs baseline: 2.5107x; 1.1500x over previous
//
#include <hip/hip_runtime.h>
#include <math.h>

#define S_LEN 4096
#define DMODEL 1024
#define NHEADS 16
#define DHEAD 64

typedef unsigned short u16;
typedef short bf16x8 __attribute__((ext_vector_type(8)));
typedef float f32x4 __attribute__((ext_vector_type(4)));
typedef u16 u16x4 __attribute__((ext_vector_type(4)));
typedef u16 u16x8 __attribute__((ext_vector_type(8)));
typedef unsigned uint4v __attribute__((ext_vector_type(4)));

__device__ __forceinline__ u16 f2bf(float f) {
    unsigned u = __builtin_bit_cast(unsigned, f);
    u = (u + 0x7FFFu + ((u >> 16) & 1u)) >> 16;
    return (u16)u;
}
__device__ __forceinline__ float bf2f(u16 b) {
    return __builtin_bit_cast(float, ((unsigned)b) << 16);
}

// async global->LDS, 16B per lane; LDS dest = wave-uniform base + lane*16
__device__ __forceinline__ void gload16(const void* g, void* l) {
    __builtin_amdgcn_global_load_lds((const __attribute__((address_space(1))) void*)g,
                                     (__attribute__((address_space(3))) void*)l, 16, 0, 0);
}

// ---------------- RoPE tables (fp32-faithful to numpy float32 path) ----------------
__global__ void rope_table_kernel(float* __restrict__ cost, float* __restrict__ sint) {
    int tid = blockIdx.x * blockDim.x + threadIdx.x;  // 4096*32
    int i = tid & 31;
    int pos = tid >> 5;
    double e = (double)(2 * i) / 64.0;
    float t32 = (float)pow(10000.0, e);
    float freq = 1.0f / t32;
    float ang = (float)pos * freq;
    cost[tid] = (float)cos((double)ang);
    sint[tid] = (float)sin((double)ang);
}

// ---------------- fp32 -> bf16 hi (+ optional lo residual) ----------------
__global__ void split_kernel(const float* __restrict__ in, u16* __restrict__ hi,
                             u16* __restrict__ lo, int n4) {
    int i = blockIdx.x * blockDim.x + threadIdx.x;
    if (i >= n4) return;
    float4 v = ((const float4*)in)[i];
    float f[4] = {v.x, v.y, v.z, v.w};
    u16x4 h, l;
#pragma unroll
    for (int j = 0; j < 4; j++) {
        h[j] = f2bf(f[j]);
        l[j] = f2bf(f[j] - bf2f(h[j]));
    }
    ((u16x4*)hi)[i] = h;
    if (lo) ((u16x4*)lo)[i] = l;
}

// ---------------- QKV GEMM (pre-split bf16 inputs) + fused RoPE ----------------
// C[128x128] tile; acc = AL*BH + AH*BL + AH*BH (fp32 MFMA accumulate).
// z=0 -> Q2 bf16 hi/lo [h][s][128] (RoPE, pre-scaled 1/8); z=1 -> K2; z=2 -> V^T [h*64+d][s].
__global__ __launch_bounds__(256) void gemm_qkv_kernel(
        const u16* __restrict__ xh, const u16* __restrict__ xl,
        const u16* __restrict__ wh3, const u16* __restrict__ wl3,
        const int* __restrict__ tp,
        const float* __restrict__ cost, const float* __restrict__ sint,
        u16* __restrict__ q2, u16* __restrict__ k2, u16* __restrict__ vtb) {
    __shared__ u16 sAH[128 * 32], sAL[128 * 32], sBH[128 * 32], sBL[128 * 32];
    const int z = blockIdx.z;
    const u16* BH = wh3 + (size_t)z * 1048576;
    const u16* BL = wl3 + (size_t)z * 1048576;
    const int m0 = blockIdx.y * 128, n0 = blockIdx.x * 128;

    const int tid = threadIdx.x;
    const int lane = tid & 63, wid = tid >> 6;
    const int wr = wid >> 1, wc = wid & 1;
    const int l15 = lane & 15, lhi = lane >> 4;

    f32x4 acc[4][4];
#pragma unroll
    for (int i = 0; i < 4; i++)
#pragma unroll
        for (int j = 0; j < 4; j++) acc[i][j] = (f32x4){0.f, 0.f, 0.f, 0.f};

    for (int kt = 0; kt < 1024; kt += 32) {
        // stage 4 tiles via global_load_lds: wave wid covers rows [wid*32, wid*32+32)
#pragma unroll
        for (int i = 0; i < 2; i++) {
            const int rbase = wid * 32 + i * 16;
            const int row = rbase + (lane >> 2);
            const size_t aoff = (size_t)(m0 + row) * 1024 + kt + (lane & 3) * 8;
            const size_t boff = (size_t)(n0 + row) * 1024 + kt + (lane & 3) * 8;
            gload16(xh + aoff, sAH + rbase * 32);
            gload16(xl + aoff, sAL + rbase * 32);
            gload16(BH + boff, sBH + rbase * 32);
            gload16(BL + boff, sBL + rbase * 32);
        }
        __syncthreads();
        bf16x8 ah[4], al[4], bh[4], bl[4];
#pragma unroll
        for (int m = 0; m < 4; m++) {
            int row = wr * 64 + m * 16 + l15;
            ah[m] = *(const bf16x8*)(sAH + row * 32 + 8 * lhi);
            al[m] = *(const bf16x8*)(sAL + row * 32 + 8 * lhi);
        }
#pragma unroll
        for (int n = 0; n < 4; n++) {
            int row = wc * 64 + n * 16 + l15;
            bh[n] = *(const bf16x8*)(sBH + row * 32 + 8 * lhi);
            bl[n] = *(const bf16x8*)(sBL + row * 32 + 8 * lhi);
        }
#pragma unroll
        for (int m = 0; m < 4; m++)
#pragma unroll
            for (int n = 0; n < 4; n++) {
                acc[m][n] = __builtin_amdgcn_mfma_f32_16x16x32_bf16(al[m], bh[n], acc[m][n], 0, 0, 0);
                acc[m][n] = __builtin_amdgcn_mfma_f32_16x16x32_bf16(ah[m], bl[n], acc[m][n], 0, 0, 0);
                acc[m][n] = __builtin_amdgcn_mfma_f32_16x16x32_bf16(ah[m], bh[n], acc[m][n], 0, 0, 0);
            }
        __syncthreads();
    }

    if (z == 2) {
#pragma unroll
        for (int m = 0; m < 4; m++)
#pragma unroll
            for (int n = 0; n < 4; n++)
#pragma unroll
                for (int j = 0; j < 4; j++) {
                    int srow = m0 + wr * 64 + m * 16 + lhi * 4 + j;
                    int eg = n0 + wc * 64 + n * 16 + l15;
                    vtb[(size_t)eg * S_LEN + srow] = f2bf(acc[m][n][j]);
                }
        return;
    }

    u16* outp = (z == 0) ? q2 : k2;
    const float qscale = (z == 0) ? 0.125f : 1.0f;   // fold 1/sqrt(64) into Q (exact pow2)
    const int head = (n0 + wc * 64) >> 6;
#pragma unroll
    for (int m = 0; m < 4; m++)
#pragma unroll
        for (int n = 0; n < 4; n++) {
            const int dh = n * 16 + l15;
            const int pairi = dh >> 1;
            const bool even = (dh & 1) == 0;
#pragma unroll
            for (int j = 0; j < 4; j++) {
                int srow = m0 + wr * 64 + m * 16 + lhi * 4 + j;
                float v = acc[m][n][j];
                float pv = __shfl_xor(v, 1);
                int pos = tp[srow];
                float cc = cost[(size_t)pos * 32 + pairi];
                float ss = sint[(size_t)pos * 32 + pairi];
                float e = even ? v : pv;
                float o = even ? pv : v;
                float res = (even ? (e * cc - o * ss) : (e * ss + o * cc)) * qscale;
                u16 hb = f2bf(res);
                u16 lb = f2bf(res - bf2f(hb));
                size_t base = ((size_t)head * S_LEN + srow) * 128 + dh;
                outp[base] = hb;
                outp[base + 64] = lb;
            }
        }
}

// ---------------- Flash attention: paired q-tiles + LDS-staged K/V double buffer ----------------
#define PLD32 33
__global__ __launch_bounds__(256) void attn_kernel(const u16* __restrict__ q2,
                                                   const u16* __restrict__ k2,
                                                   const u16* __restrict__ vtb,
                                                   u16* __restrict__ attnb) {
    const int h = blockIdx.y;
    const int p = blockIdx.x;              // pair id 0..15 -> tiles (31-p, p)
    const int wid = threadIdx.x >> 6;
    const int lane = threadIdx.x & 63;
    const int l15 = lane & 15, lhi = lane >> 4;

    const u16* Qh2 = q2 + (size_t)h * S_LEN * 128;
    const u16* Kh2 = k2 + (size_t)h * S_LEN * 128;
    const u16* Vh  = vtb + (size_t)h * 64 * S_LEN;

    __shared__ u16 sK[2][64 * 128];
    __shared__ u16 sV[2][64 * 64];
    __shared__ unsigned pls[4][32 * PLD32];
    unsigned* myP = pls[wid];

    const int tileA = 31 - p, tileB = p;
    const int eA = 2 * tileA + 2, eB = 2 * tileB + 2;
    const int etot = eA + eB;              // 66 for every block

    auto stage = [&](int t, int b) {
        const int k = (t < eA) ? t : (t - eA);
        const int k0 = k * 64;
#pragma unroll
        for (int i = 0; i < 4; i++) {
            const int rbase = wid * 16 + i * 4;
            const int row = rbase + (lane >> 4);
            const int cb = (lane & 15) * 16;
            const int csw = cb ^ ((row & 7) << 4);
            gload16(Kh2 + (size_t)(k0 + row) * 128 + (csw >> 1), &sK[b][rbase * 128]);
        }
#pragma unroll
        for (int i = 0; i < 2; i++) {
            const int rbase = wid * 16 + i * 8;
            const int row = rbase + (lane >> 3);
            const int cb = (lane & 7) * 16;
            const int csw = cb ^ ((row & 7) << 4);
            gload16(Vh + (size_t)row * S_LEN + k0 + (csw >> 1), &sV[b][rbase * 64]);
        }
    };

    bf16x8 qhf[2][2], qlf[2][2];
    f32x4 oT[2][4];
    float m_run[2], l_run[2];
    int q0 = 0, my_nkb = 0;

    auto initPass = [&](int tile) {
        q0 = tile * 128 + wid * 32;
        my_nkb = ((q0 + 31) >> 6) + 1;
#pragma unroll
        for (int g = 0; g < 2; g++)
#pragma unroll
            for (int ks = 0; ks < 2; ks++) {
                const u16* qp = Qh2 + (size_t)(q0 + g * 16 + l15) * 128 + ks * 32 + 8 * lhi;
                qhf[g][ks] = *(const bf16x8*)(qp);
                qlf[g][ks] = *(const bf16x8*)(qp + 64);
            }
#pragma unroll
        for (int g = 0; g < 2; g++) {
            m_run[g] = -1e30f;
            l_run[g] = 0.f;
#pragma unroll
            for (int m = 0; m < 4; m++) oT[g][m] = (f32x4){0.f, 0.f, 0.f, 0.f};
        }
    };

    auto writeOut = [&]() {
#pragma unroll
        for (int g = 0; g < 2; g++) {
            const int srow = q0 + g * 16 + l15;
            const float inv = 1.0f / l_run[g];
#pragma unroll
            for (int m = 0; m < 4; m++)
#pragma unroll
                for (int j = 0; j < 4; j++)
                    attnb[(size_t)srow * 1024 + h * 64 + m * 16 + lhi * 4 + j] =
                        f2bf(oT[g][m][j] * inv);
        }
    };

    stage(0, 0);
    initPass(tileA);
    __syncthreads();

    int cur = 0;
    for (int t = 0; t < etot; ++t) {
        if (t + 1 < etot) stage(t + 1, cur ^ 1);
        if (t == eA) { writeOut(); initPass(tileB); }
        const int k = (t < eA) ? t : (t - eA);
        if (k < my_nkb) {
            const int k0 = k * 64;
            bf16x8 kh[4][2], kl[4][2], vfr[4][2];
#pragma unroll
            for (int m = 0; m < 4; m++) {
                const int r = m * 16 + l15;
                const int sw = (r & 7) << 4;
                const u16* kp = &sK[cur][r * 128];
                const u16* vp = &sV[cur][r * 64];
#pragma unroll
                for (int c = 0; c < 2; c++) {
                    kh[m][c] = *(const bf16x8*)(kp + (((c * 64 + lhi * 16) ^ sw) >> 1));
                    kl[m][c] = *(const bf16x8*)(kp + (((128 + c * 64 + lhi * 16) ^ sw) >> 1));
                    vfr[m][c] = *(const bf16x8*)(vp + (((c * 64 + lhi * 16) ^ sw) >> 1));
                }
            }
            f32x4 sT[4][2];
#pragma unroll
            for (int m = 0; m < 4; m++)
#pragma unroll
                for (int g = 0; g < 2; g++) {
                    f32x4 a = (f32x4){0.f, 0.f, 0.f, 0.f};
                    a = __builtin_amdgcn_mfma_f32_16x16x32_bf16(kh[m][0], qlf[g][0], a, 0, 0, 0);
                    a = __builtin_amdgcn_mfma_f32_16x16x32_bf16(kh[m][1], qlf[g][1], a, 0, 0, 0);
                    a = __builtin_amdgcn_mfma_f32_16x16x32_bf16(kl[m][0], qhf[g][0], a, 0, 0, 0);
                    a = __builtin_amdgcn_mfma_f32_16x16x32_bf16(kl[m][1], qhf[g][1], a, 0, 0, 0);
                    a = __builtin_amdgcn_mfma_f32_16x16x32_bf16(kh[m][0], qhf[g][0], a, 0, 0, 0);
                    a = __builtin_amdgcn_mfma_f32_16x16x32_bf16(kh[m][1], qhf[g][1], a, 0, 0, 0);
                    sT[m][g] = a;
                }
            const bool last = (k == my_nkb - 1);
#pragma unroll
            for (int g = 0; g < 2; g++) {
                const int qg = q0 + g * 16 + l15;
                if (last) {
#pragma unroll
                    for (int m = 0; m < 4; m++)
#pragma unroll
                        for (int j = 0; j < 4; j++) {
                            int kg = k0 + m * 16 + lhi * 4 + j;
                            if (kg > qg) sT[m][g][j] = -1e30f;
                        }
                }
                float t0 = fmaxf(fmaxf(sT[0][g][0], sT[0][g][1]), fmaxf(sT[0][g][2], sT[0][g][3]));
                float t1 = fmaxf(fmaxf(sT[1][g][0], sT[1][g][1]), fmaxf(sT[1][g][2], sT[1][g][3]));
                float t2 = fmaxf(fmaxf(sT[2][g][0], sT[2][g][1]), fmaxf(sT[2][g][2], sT[2][g][3]));
                float t3 = fmaxf(fmaxf(sT[3][g][0], sT[3][g][1]), fmaxf(sT[3][g][2], sT[3][g][3]));
                float mx = fmaxf(fmaxf(t0, t1), fmaxf(t2, t3));
                mx = fmaxf(mx, __shfl_xor(mx, 16));
                mx = fmaxf(mx, __shfl_xor(mx, 32));
                float mn = fmaxf(m_run[g], mx);
                float alpha = __expf(m_run[g] - mn);
                float s0 = 0.f, s1 = 0.f, s2 = 0.f, s3 = 0.f;
#pragma unroll
                for (int m = 0; m < 4; m++) {
                    float p0 = __expf(sT[m][g][0] - mn);
                    float p1 = __expf(sT[m][g][1] - mn);
                    float p2 = __expf(sT[m][g][2] - mn);
                    float p3 = __expf(sT[m][g][3] - mn);
                    sT[m][g][0] = p0; sT[m][g][1] = p1; sT[m][g][2] = p2; sT[m][g][3] = p3;
                    s0 += p0; s1 += p1; s2 += p2; s3 += p3;
                }
                float rs = (s0 + s1) + (s2 + s3);
                rs += __shfl_xor(rs, 16);
                rs += __shfl_xor(rs, 32);
                l_run[g] = l_run[g] * alpha + rs;
                m_run[g] = mn;
#pragma unroll
                for (int m = 0; m < 4; m++) {
                    oT[g][m][0] *= alpha; oT[g][m][1] *= alpha;
                    oT[g][m][2] *= alpha; oT[g][m][3] *= alpha;
                }
#pragma unroll
                for (int m = 0; m < 4; m++)
#pragma unroll
                    for (int jj = 0; jj < 2; jj++) {
                        unsigned pk = (unsigned)f2bf(sT[m][g][2 * jj]) |
                                      ((unsigned)f2bf(sT[m][g][2 * jj + 1]) << 16);
                        myP[(g * 16 + l15) * PLD32 + m * 8 + lhi * 2 + jj] = pk;
                    }
            }
            bf16x8 pf[2][2];
#pragma unroll
            for (int g = 0; g < 2; g++)
#pragma unroll
                for (int ks = 0; ks < 2; ks++) {
                    uint4v pw = *(const uint4v*)(myP + (g * 16 + l15) * PLD32 + ks * 16 + 4 * lhi);
                    pf[g][ks] = __builtin_bit_cast(bf16x8, pw);
                }
#pragma unroll
            for (int g = 0; g < 2; g++)
#pragma unroll
                for (int m = 0; m < 4; m++) {
                    oT[g][m] = __builtin_amdgcn_mfma_f32_16x16x32_bf16(vfr[m][0], pf[g][0], oT[g][m], 0, 0, 0);
                    oT[g][m] = __builtin_amdgcn_mfma_f32_16x16x32_bf16(vfr[m][1], pf[g][1], oT[g][m], 0, 0, 0);
                }
        }
        __syncthreads();
        cur ^= 1;
    }
    writeOut();
}

// ---------------- output projection: bf16 x bf16 -> fp32, gload16-staged ----------------
__global__ __launch_bounds__(256) void gemm_out_kernel(const u16* __restrict__ attnb,
                                                       const u16* __restrict__ woh,
                                                       float* __restrict__ out) {
    __shared__ u16 sA[128 * 32];
    __shared__ u16 sB[128 * 32];
    const int m0 = blockIdx.y * 128, n0 = blockIdx.x * 128;
    const int tid = threadIdx.x;
    const int lane = tid & 63, wid = tid >> 6;
    const int wr = wid >> 1, wc = wid & 1;
    const int l15 = lane & 15, lhi = lane >> 4;

    f32x4 acc[4][4];
#pragma unroll
    for (int i = 0; i < 4; i++)
#pragma unroll
        for (int j = 0; j < 4; j++) acc[i][j] = (f32x4){0.f, 0.f, 0.f, 0.f};

    for (int kt = 0; kt < 1024; kt += 32) {
#pragma unroll
        for (int i = 0; i < 2; i++) {
            const int rbase = wid * 32 + i * 16;
            const int row = rbase + (lane >> 2);
            gload16(attnb + (size_t)(m0 + row) * 1024 + kt + (lane & 3) * 8, sA + rbase * 32);
            gload16(woh + (size_t)(n0 + row) * 1024 + kt + (lane & 3) * 8, sB + rbase * 32);
        }
        __syncthreads();
        bf16x8 af[4], bfr[4];
#pragma unroll
        for (int m = 0; m < 4; m++) {
            int row = wr * 64 + m * 16 + l15;
            af[m] = *(const bf16x8*)(sA + row * 32 + 8 * lhi);
        }
#pragma unroll
        for (int n = 0; n < 4; n++) {
            int row = wc * 64 + n * 16 + l15;
            bfr[n] = *(const bf16x8*)(sB + row * 32 + 8 * lhi);
        }
#pragma unroll
        for (int m = 0; m < 4; m++)
#pragma unroll
            for (int n = 0; n < 4; n++)
                acc[m][n] = __builtin_amdgcn_mfma_f32_16x16x32_bf16(af[m], bfr[n], acc[m][n], 0, 0, 0);
        __syncthreads();
    }

#pragma unroll
    for (int m = 0; m < 4; m++)
#pragma unroll
        for (int n = 0; n < 4; n++)
#pragma unroll
            for (int j = 0; j < 4; j++) {
                int srow = m0 + wr * 64 + m * 16 + lhi * 4 + j;
                int eg = n0 + wc * 64 + n * 16 + l15;
                out[(size_t)srow * 1024 + eg] = acc[m][n][j];
            }
}

// ---------------- host launch ----------------
extern "C" void kernel_launch(void* const* d_in, const int* in_sizes, int n_in,
                              void* d_out, int out_size, void* d_ws, size_t ws_size,
                              hipStream_t stream) {
    const float* x = (const float*)d_in[0];
    const int* tp = (const int*)d_in[1];
    const float* wq = (const float*)d_in[2];
    const float* wk = (const float*)d_in[3];
    const float* wv = (const float*)d_in[4];
    const float* wo = (const float*)d_in[5];
    float* out = (float*)d_out;
    char* ws = (char*)d_ws;

    u16* Q2    = (u16*)(ws + 0);           // 16 MiB bf16 [16][4096][128] hi/lo, Q pre-scaled 1/8
    u16* K2    = (u16*)(ws + 16777216);    // 16 MiB
    u16* VTB   = (u16*)(ws + 33554432);    // 8 MiB bf16 [h*64+dh][4096]
    u16* ATTNB = (u16*)(ws + 41943040);    // 8 MiB bf16 [4096][1024]
    float* COST = (float*)(ws + 50331648); // 512 KiB
    float* SINT = (float*)(ws + 50855936); // 512 KiB
    u16* XH  = (u16*)(ws + 51380224);      // 8 MiB bf16 [4096][1024]
    u16* XL  = (u16*)(ws + 59768832);      // 8 MiB
    u16* WH3 = (u16*)(ws + 68157440);      // 6 MiB bf16 [3][1024][1024]
    u16* WL3 = (u16*)(ws + 74448896);      // 6 MiB
    u16* WOH = (u16*)(ws + 80740352);      // 2 MiB bf16 [1024][1024]

    rope_table_kernel<<<512, 256, 0, stream>>>(COST, SINT);

    split_kernel<<<4096, 256, 0, stream>>>(x, XH, XL, 1048576);
    split_kernel<<<1024, 256, 0, stream>>>(wq, WH3,            WL3,            262144);
    split_kernel<<<1024, 256, 0, stream>>>(wk, WH3 + 1048576,  WL3 + 1048576,  262144);
    split_kernel<<<1024, 256, 0, stream>>>(wv, WH3 + 2097152,  WL3 + 2097152,  262144);
    split_kernel<<<1024, 256, 0, stream>>>(wo, WOH,            (u16*)nullptr,  262144);

    gemm_qkv_kernel<<<dim3(8, 32, 3), 256, 0, stream>>>(
        XH, XL, WH3, WL3, tp, COST, SINT, Q2, K2, VTB);

    attn_kernel<<<dim3(16, 16), 256, 0, stream>>>(Q2, K2, VTB, ATTNB);

    gemm_out_kernel<<<dim3(8, 32), 256, 0, stream>>>(ATTNB, WOH, out);
}